// Round 18
// baseline (58.759 us; speedup 1.0000x reference)
//
#include <hip/hip_runtime.h>
#include <stdint.h>

typedef uint16_t u16;
typedef __attribute__((ext_vector_type(2))) float f32x2;
typedef __attribute__((ext_vector_type(4))) float f32x4;
typedef __attribute__((ext_vector_type(8))) short short8;
typedef __attribute__((ext_vector_type(4))) float float4v;
typedef __attribute__((ext_vector_type(4))) uint16_t u16x4;
typedef __attribute__((ext_vector_type(8))) uint16_t u16x8;

#define DIMQ 1024
#define BATCH 8192
#define KDIM 1024
#define NDIM 1024

#define RDL(v, l) __int_as_float(__builtin_amdgcn_readlane(__float_as_int(v), (l)))

__device__ __forceinline__ u16 f2bf(float f) {
  uint32_t u = __float_as_uint(f);
  u += 0x7fffu + ((u >> 16) & 1u);
  return (u16)(u >> 16);
}

// cross-lane xor exchange; DPP (VALU) for 1,2,8; ds_swizzle for 4,16; shfl for 32.
// (verified R4/R5/R6/R11/R15)
template<int MASK>
__device__ __forceinline__ float lane_xor(float x) {
  if constexpr (MASK == 1)
    return __int_as_float(__builtin_amdgcn_update_dpp(0, __float_as_int(x), 0xB1, 0xF, 0xF, true));
  else if constexpr (MASK == 2)
    return __int_as_float(__builtin_amdgcn_update_dpp(0, __float_as_int(x), 0x4E, 0xF, 0xF, true));
  else if constexpr (MASK == 8)
    return __int_as_float(__builtin_amdgcn_update_dpp(0, __float_as_int(x), 0x128, 0xF, 0xF, true));
  else if constexpr (MASK == 4)
    return __int_as_float(__builtin_amdgcn_ds_swizzle(__float_as_int(x), 0x101F));
  else if constexpr (MASK == 16)
    return __int_as_float(__builtin_amdgcn_ds_swizzle(__float_as_int(x), 0x401F));
  else
    return __shfl_xor(x, 32, 64);
}

// cross-lane gate on 4 regs: batched partner fetch, then PACKED FMAs
// (R14's verified lane_gate8 with 4 regs)
template<int MASK>
__device__ __forceinline__ void lane_gate4(float* ar, float* ai, int lane,
    float u00r, float u00i, float u01r, float u01i,
    float u10r, float u10i, float u11r, float u11i) {
  bool hi = (lane & MASK) != 0;
  float cmr = hi ? u11r : u00r, cmi = hi ? u11i : u00i;
  float cor = hi ? u10r : u01r, coi = hi ? u10i : u01i;
  float otr[4], oti[4];
#pragma unroll
  for (int r = 0; r < 4; ++r) otr[r] = lane_xor<MASK>(ar[r]);
#pragma unroll
  for (int r = 0; r < 4; ++r) oti[r] = lane_xor<MASK>(ai[r]);
#pragma unroll
  for (int k = 0; k < 2; ++k) {
    f32x2 A = {ar[2*k], ar[2*k+1]}, I = {ai[2*k], ai[2*k+1]};
    f32x2 R = {otr[2*k], otr[2*k+1]}, J = {oti[2*k], oti[2*k+1]};
    f32x2 nr = A*cmr - I*cmi + R*cor - J*coi;
    f32x2 ni = I*cmr + A*cmi + J*cor + R*coi;
    ar[2*k] = nr[0]; ar[2*k+1] = nr[1];
    ai[2*k] = ni[0]; ai[2*k+1] = ni[1];
  }
}

// packed 2x2 butterfly on two amp pairs at once (verified R14)
__device__ __forceinline__ void bfly2(f32x2 &a0r, f32x2 &a0i, f32x2 &a1r, f32x2 &a1i,
    float u00r, float u00i, float u01r, float u01i,
    float u10r, float u10i, float u11r, float u11i) {
  f32x2 t0r = a0r*u00r - a0i*u00i + a1r*u01r - a1i*u01i;
  f32x2 t0i = a0i*u00r + a0r*u00i + a1i*u01r + a1r*u01i;
  f32x2 t1r = a0r*u10r - a0i*u10i + a1r*u11r - a1i*u11i;
  f32x2 t1i = a0i*u10r + a0r*u10i + a1i*u11r + a1r*u11i;
  a0r = t0r; a0i = t0i; a1r = t1r; a1i = t1i;
}

// complex 2x2 layout: {00r,00i, 01r,01i, 10r,10i, 11r,11i}
__device__ inline void cmul2x2(float* O, const float* A, const float* B) {
  for (int r = 0; r < 2; ++r)
    for (int c = 0; c < 2; ++c) {
      float re = 0.f, im = 0.f;
      for (int j = 0; j < 2; ++j) {
        float ar = A[(r*2+j)*2], ai = A[(r*2+j)*2+1];
        float br = B[(j*2+c)*2], bi = B[(j*2+c)*2+1];
        re += ar*br - ai*bi;
        im += ar*bi + ai*br;
      }
      O[(r*2+c)*2]   = re;
      O[(r*2+c)*2+1] = im;
    }
}
__device__ inline void mk_rx(float* m, float t) {
  float s, c; sincosf(0.5f*t, &s, &c);
  m[0]=c; m[1]=0; m[2]=0; m[3]=-s; m[4]=0; m[5]=-s; m[6]=c; m[7]=0;
}
__device__ inline void mk_ry(float* m, float t) {
  float s, c; sincosf(0.5f*t, &s, &c);
  m[0]=c; m[1]=0; m[2]=-s; m[3]=0; m[4]=s; m[5]=0; m[6]=c; m[7]=0;
}
__device__ inline void mk_rz(float* m, float t) {
  float s, c; sincosf(0.5f*t, &s, &c);
  m[0]=c; m[1]=-s; m[2]=0; m[3]=0; m[4]=0; m[5]=0; m[6]=c; m[7]=s;
}

__device__ __forceinline__ int padi(int y) { return y + (y >> 4); }

// Fused front: 4 waves per basis state.
//   blocks [0, 1024):       build — ONE state d=bid; amp x = (lane<<4)|(wv<<2)|j.
//     bits [9:4]=lane (lane gates), [3:2]=wv (fused into LDS pass as K=U6⊗U7),
//     [1:0]=j (packed bflys). Per stage: one LDS gather (perm ∘ wave-bit gates),
//     reg gates, lane gates. Stage 0 = closed-form Kronecker init (R15).
//   blocks [1024, 1536):    norm — 16 rows/block (R15 exact).
__global__ __launch_bounds__(256) void fused_front(const float* __restrict__ x,
                                                   const float* __restrict__ w,
                                                   u16* __restrict__ Abf,
                                                   u16* __restrict__ Bmat) {
  __shared__ f32x2 slab[1088];   // one state, padded: 8.7 KB
  const int bid = blockIdx.x;
  const int lane = threadIdx.x & 63, wv = threadIdx.x >> 6;

  if (bid >= 1024) {
    // ---- normalize path: 16 rows/block, 4 per wave ----
    int base = (bid - 1024) * 16 + wv * 4;
    for (int it = 0; it < 4; ++it) {
      int row = base + it;
      const float* xr = x + (size_t)row * DIMQ;
      float4v v[4];
      float ss = 0.f;
#pragma unroll
      for (int j = 0; j < 4; ++j) {
        v[j] = *(const float4v*)(xr + j*256 + lane*4);
        ss += v[j][0]*v[j][0] + v[j][1]*v[j][1] + v[j][2]*v[j][2] + v[j][3]*v[j][3];
      }
#pragma unroll
      for (int off = 32; off; off >>= 1) ss += __shfl_xor(ss, off, 64);
      float inv = 1.0f / fmaxf(sqrtf(ss), 1e-12f);
      u16* orow = Abf + (size_t)row * DIMQ;
#pragma unroll
      for (int j = 0; j < 4; ++j) {
        u16x4 o;
#pragma unroll
        for (int e = 0; e < 4; ++e) o[e] = f2bf(v[j][e] * inv);
        *(u16x4*)(orow + j*256 + lane*4) = o;
      }
    }
    return;
  }

  // ---- build path: state d = bid, this wave owns amp bits [3:2] = wv ----
  const int d = bid;

  // lanes 0..49: the 50 fused ADJOINT gate matrices (verified R5)
  float O0, O1, O2, O3, O4, O5, O6, O7;
  {
    float A[8], B[8], C[8], T8[8], O[8];
    int t = lane;
    if (t < 50) {
      if (t < 10) {
        mk_ry(A, -w[120 + t]);
        mk_rz(B, -w[130 + t]);
        mk_ry(C, -w[140 + t]);
      } else {
        int sg = (t - 10) / 10, q = (t - 10) % 10, l = 3 - sg;
        mk_rx(A, -w[l*30 + q]);
        mk_ry(B, -w[l*30 + 10 + q]);
        mk_rz(C, -w[l*30 + 20 + q]);
      }
      cmul2x2(T8, A, B);
      cmul2x2(O, T8, C);
    } else {
#pragma unroll
      for (int j = 0; j < 8; ++j) O[j] = 0.f;
    }
    O0=O[0]; O1=O[1]; O2=O[2]; O3=O[3]; O4=O[4]; O5=O[5]; O6=O[6]; O7=O[7];
  }

  // gather indices: sigma GF(2)-linear (verified R6/R11).
  // target x (bits32=wv) gathers from sigma(x with bits32=w') = yj[j] ^ T[w'].
  // T[w'] = sigma(w'<<2) = {0, 519, 527, 8}  (T[3]=T[1]^T[2] by linearity).
  int idP[4][4];   // [j][w'], padded f32x2 units
  {
    const int T[4] = {0, 519, 527, 8};
#pragma unroll
    for (int j = 0; j < 4; ++j) {
      int xx = (lane << 4) | j;
      int yy = xx;
#pragma unroll
      for (int qq = 0; qq < 9; ++qq) yy ^= ((yy >> (9 - qq)) & 1) << (8 - qq);
      yy ^= (yy & 1) << 9;
#pragma unroll
      for (int wp = 0; wp < 4; ++wp) idP[j][wp] = padi(yy ^ T[wp]);
    }
  }
  const int wbase = lane * 17 + wv * 4;   // padi((lane<<4)|(wv<<2)|j) = wbase + j

  // ---- STAGE 0 closed form (R15 verified, adapted): amp = f * m[j]
  //      f = prod of lane-bit factors (p4..9) and wave-bit factors (p3,p2);
  //      m[j] = t1[j>>1] (x) t0[j&1]  (p1=q8, p0=q9)
  float ar[4], ai[4];
  {
    float fr = 1.0f, fi = 0.0f;
#pragma unroll
    for (int p = 4; p <= 9; ++p) {
      const int q = 9 - p;
      int c = (d >> p) & 1;
      float a0r = c ? RDL(O2,q) : RDL(O0,q), a0i = c ? RDL(O3,q) : RDL(O1,q);
      float a1r = c ? RDL(O6,q) : RDL(O4,q), a1i = c ? RDL(O7,q) : RDL(O5,q);
      bool hb = (lane >> (p - 4)) & 1;
      float gr = hb ? a1r : a0r, gi = hb ? a1i : a0i;
      float nr = fr*gr - fi*gi, ni = fr*gi + fi*gr;
      fr = nr; fi = ni;
    }
    {  // p=3 -> q6, row = wv>>1
      int c = (d >> 3) & 1;
      float a0r = c ? RDL(O2,6) : RDL(O0,6), a0i = c ? RDL(O3,6) : RDL(O1,6);
      float a1r = c ? RDL(O6,6) : RDL(O4,6), a1i = c ? RDL(O7,6) : RDL(O5,6);
      bool hb = (wv >> 1) & 1;
      float gr = hb ? a1r : a0r, gi = hb ? a1i : a0i;
      float nr = fr*gr - fi*gi, ni = fr*gi + fi*gr;
      fr = nr; fi = ni;
    }
    {  // p=2 -> q7, row = wv&1
      int c = (d >> 2) & 1;
      float a0r = c ? RDL(O2,7) : RDL(O0,7), a0i = c ? RDL(O3,7) : RDL(O1,7);
      float a1r = c ? RDL(O6,7) : RDL(O4,7), a1i = c ? RDL(O7,7) : RDL(O5,7);
      bool hb = wv & 1;
      float gr = hb ? a1r : a0r, gi = hb ? a1i : a0i;
      float nr = fr*gr - fi*gi, ni = fr*gi + fi*gr;
      fr = nr; fi = ni;
    }
    float t1r[2], t1i[2], t0r[2], t0i[2];
    {  // p=1 -> q8
      int c = (d >> 1) & 1;
      t1r[0] = c ? RDL(O2,8) : RDL(O0,8); t1i[0] = c ? RDL(O3,8) : RDL(O1,8);
      t1r[1] = c ? RDL(O6,8) : RDL(O4,8); t1i[1] = c ? RDL(O7,8) : RDL(O5,8);
    }
    {  // p=0 -> q9
      int c = d & 1;
      t0r[0] = c ? RDL(O2,9) : RDL(O0,9); t0i[0] = c ? RDL(O3,9) : RDL(O1,9);
      t0r[1] = c ? RDL(O6,9) : RDL(O4,9); t0i[1] = c ? RDL(O7,9) : RDL(O5,9);
    }
#pragma unroll
    for (int j = 0; j < 4; ++j) {
      int b1 = j >> 1, b0 = j & 1;
      float mr = t1r[b1]*t0r[b0] - t1i[b1]*t0i[b0];
      float mi = t1r[b1]*t0i[b0] + t1i[b1]*t0r[b0];
      ar[j] = fr*mr - fi*mi;
      ai[j] = fr*mi + fi*mr;
    }
  }

  // ---- stages 1..4 ----
#pragma clang loop unroll(disable)
  for (int stage = 1; stage < 5; ++stage) {
    const int gbase = stage * 10;
    // LDS pass: perm + wave-bit gates q6,q7 fused as K = U6 (x) U7, row = wv
    __syncthreads();
#pragma unroll
    for (int j = 0; j < 4; ++j) slab[wbase + j] = (f32x2){ar[j], ai[j]};
    __syncthreads();
    {
      int g6 = gbase + 6, g7 = gbase + 7;
      bool r6 = (wv >> 1) & 1, r7 = wv & 1;
      // U6[wv>>1][c], U7[wv&1][c]
      float u6r[2], u6i[2], u7r[2], u7i[2];
      u6r[0] = r6 ? RDL(O4,g6) : RDL(O0,g6); u6i[0] = r6 ? RDL(O5,g6) : RDL(O1,g6);
      u6r[1] = r6 ? RDL(O6,g6) : RDL(O2,g6); u6i[1] = r6 ? RDL(O7,g6) : RDL(O3,g6);
      u7r[0] = r7 ? RDL(O4,g7) : RDL(O0,g7); u7i[0] = r7 ? RDL(O5,g7) : RDL(O1,g7);
      u7r[1] = r7 ? RDL(O6,g7) : RDL(O2,g7); u7i[1] = r7 ? RDL(O7,g7) : RDL(O3,g7);
      float Kr[4], Ki[4];   // K[w'] = U6[.][w'>>1] * U7[.][w'&1]
#pragma unroll
      for (int wp = 0; wp < 4; ++wp) {
        int c6 = wp >> 1, c7 = wp & 1;
        Kr[wp] = u6r[c6]*u7r[c7] - u6i[c6]*u7i[c7];
        Ki[wp] = u6r[c6]*u7i[c7] + u6i[c6]*u7r[c7];
      }
      f32x2 v[4][4];
#pragma unroll
      for (int j = 0; j < 4; ++j)
#pragma unroll
        for (int wp = 0; wp < 4; ++wp) v[j][wp] = slab[idP[j][wp]];
#pragma unroll
      for (int k = 0; k < 2; ++k) {
        f32x2 nr = {0.f, 0.f}, ni = {0.f, 0.f};
#pragma unroll
        for (int wp = 0; wp < 4; ++wp) {
          f32x2 Vr = {v[2*k][wp][0], v[2*k+1][wp][0]};
          f32x2 Vi = {v[2*k][wp][1], v[2*k+1][wp][1]};
          nr += Vr*Kr[wp] - Vi*Ki[wp];
          ni += Vi*Kr[wp] + Vr*Ki[wp];
        }
        ar[2*k] = nr[0]; ar[2*k+1] = nr[1];
        ai[2*k] = ni[0]; ai[2*k+1] = ni[1];
      }
    }
    // reg gates: q8 (bit1: pairs (0,2),(1,3)), q9 (bit0: pairs (0,1),(2,3))
    { int g = gbase + 8;
      float u0r=RDL(O0,g),u0i=RDL(O1,g),u1r=RDL(O2,g),u1i=RDL(O3,g);
      float u2r=RDL(O4,g),u2i=RDL(O5,g),u3r=RDL(O6,g),u3i=RDL(O7,g);
      f32x2 a0r={ar[0],ar[1]}, a0i={ai[0],ai[1]}, a1r={ar[2],ar[3]}, a1i={ai[2],ai[3]};
      bfly2(a0r,a0i,a1r,a1i, u0r,u0i,u1r,u1i,u2r,u2i,u3r,u3i);
      ar[0]=a0r[0];ar[1]=a0r[1];ai[0]=a0i[0];ai[1]=a0i[1];
      ar[2]=a1r[0];ar[3]=a1r[1];ai[2]=a1i[0];ai[3]=a1i[1];
    }
    { int g = gbase + 9;
      float u0r=RDL(O0,g),u0i=RDL(O1,g),u1r=RDL(O2,g),u1i=RDL(O3,g);
      float u2r=RDL(O4,g),u2i=RDL(O5,g),u3r=RDL(O6,g),u3i=RDL(O7,g);
      f32x2 a0r={ar[0],ar[2]}, a0i={ai[0],ai[2]}, a1r={ar[1],ar[3]}, a1i={ai[1],ai[3]};
      bfly2(a0r,a0i,a1r,a1i, u0r,u0i,u1r,u1i,u2r,u2i,u3r,u3i);
      ar[0]=a0r[0];ar[2]=a0r[1];ai[0]=a0i[0];ai[2]=a0i[1];
      ar[1]=a1r[0];ar[3]=a1r[1];ai[1]=a1i[0];ai[3]=a1i[1];
    }
    // lane gates: amp bits 9..4 -> masks 32..1 (q0..q5)
    { int g = gbase + 0; lane_gate4<32>(ar, ai, lane, RDL(O0,g),RDL(O1,g),RDL(O2,g),RDL(O3,g),RDL(O4,g),RDL(O5,g),RDL(O6,g),RDL(O7,g)); }
    { int g = gbase + 1; lane_gate4<16>(ar, ai, lane, RDL(O0,g),RDL(O1,g),RDL(O2,g),RDL(O3,g),RDL(O4,g),RDL(O5,g),RDL(O6,g),RDL(O7,g)); }
    { int g = gbase + 2; lane_gate4< 8>(ar, ai, lane, RDL(O0,g),RDL(O1,g),RDL(O2,g),RDL(O3,g),RDL(O4,g),RDL(O5,g),RDL(O6,g),RDL(O7,g)); }
    { int g = gbase + 3; lane_gate4< 4>(ar, ai, lane, RDL(O0,g),RDL(O1,g),RDL(O2,g),RDL(O3,g),RDL(O4,g),RDL(O5,g),RDL(O6,g),RDL(O7,g)); }
    { int g = gbase + 4; lane_gate4< 2>(ar, ai, lane, RDL(O0,g),RDL(O1,g),RDL(O2,g),RDL(O3,g),RDL(O4,g),RDL(O5,g),RDL(O6,g),RDL(O7,g)); }
    { int g = gbase + 5; lane_gate4< 1>(ar, ai, lane, RDL(O0,g),RDL(O1,g),RDL(O2,g),RDL(O3,g),RDL(O4,g),RDL(O5,g),RDL(O6,g),RDL(O7,g)); }
  }

  // write: 4 bf16 (8 B) per lane at column lane*16 + wv*4
  u16x4 o;
#pragma unroll
  for (int j = 0; j < 4; ++j) o[j] = f2bf(ar[j]);
  *(u16x4*)(Bmat + (size_t)d * DIMQ + lane*16 + wv*4) = o;
}

// C[8192,1024] = A * B^T  (bf16 in, fp32 out) — R17 verified.
// BM=256 x BN=128, BK=64, 512 threads, dbuf LDS, T3/T4 + both-sides swizzle + T5.
__global__ __launch_bounds__(512) void gemm_bt(const u16* __restrict__ A,
                                               const u16* __restrict__ Bm,
                                               float* __restrict__ C) {
  __shared__ u16 As[2][256*64];
  __shared__ u16 Bs[2][128*64];
  const int t = threadIdx.x, lane = t & 63, wave = t >> 6;
  int bid = blockIdx.x;
  int nid = ((bid & 7) << 5) | (bid >> 3);
  const int bm = nid >> 3, bn = nid & 7;
  const size_t aBase = (size_t)bm * 256 * KDIM;
  const size_t bBase = (size_t)bn * 128 * KDIM;

  const int srow = t >> 3;
  const int scol = ((t & 7) ^ (srow & 7)) * 8;
  const int dstB = srow * 128 + (t & 7) * 16;

  const int wm = wave >> 2, wn = wave & 3;
  const int la = lane & 15;
  const int lkB = ((lane >> 4) * 16);
  const int rsw = (lane & 7) << 4;

  f32x4 acc[8][2];
#pragma unroll
  for (int m = 0; m < 8; ++m)
#pragma unroll
    for (int n = 0; n < 2; ++n) acc[m][n] = (f32x4){0.f, 0.f, 0.f, 0.f};

  auto stage = [&](int b, int kt) {
    int k0 = kt * 64;
#pragma unroll
    for (int j = 0; j < 4; ++j) {
      __builtin_amdgcn_global_load_lds(
          (const __attribute__((address_space(1))) void*)(A + aBase + (size_t)(j*64 + srow)*KDIM + k0 + scol),
          (__attribute__((address_space(3))) void*)((char*)&As[b][0] + j*8192 + dstB), 16, 0, 0);
    }
#pragma unroll
    for (int j = 0; j < 2; ++j) {
      __builtin_amdgcn_global_load_lds(
          (const __attribute__((address_space(1))) void*)(Bm + bBase + (size_t)(j*64 + srow)*KDIM + k0 + scol),
          (__attribute__((address_space(3))) void*)((char*)&Bs[b][0] + j*8192 + dstB), 16, 0, 0);
    }
  };

  stage(0, 0);
  __syncthreads();

  int cur = 0;
  for (int kt = 0; kt < 16; ++kt) {
    if (kt < 15) stage(cur ^ 1, kt + 1);
    short8 af[8][2], bf[2][2];
#pragma unroll
    for (int kk = 0; kk < 2; ++kk) {
#pragma unroll
      for (int m = 0; m < 8; ++m) {
        int row = wm*128 + m*16 + la;
        int byt = (row*128 + kk*64 + lkB) ^ rsw;
        af[m][kk] = *(const short8*)((char*)&As[cur][0] + byt);
      }
#pragma unroll
      for (int n = 0; n < 2; ++n) {
        int row = wn*32 + n*16 + la;
        int byt = (row*128 + kk*64 + lkB) ^ rsw;
        bf[n][kk] = *(const short8*)((char*)&Bs[cur][0] + byt);
      }
    }
    __builtin_amdgcn_s_setprio(1);
#pragma unroll
    for (int kk = 0; kk < 2; ++kk)
#pragma unroll
      for (int m = 0; m < 8; ++m)
#pragma unroll
        for (int n = 0; n < 2; ++n)
          acc[m][n] = __builtin_amdgcn_mfma_f32_16x16x32_bf16(af[m][kk], bf[n][kk], acc[m][n], 0, 0, 0);
    __builtin_amdgcn_s_setprio(0);
    __syncthreads();
    cur ^= 1;
  }

  int orow0 = bm*256 + wm*128 + (lane >> 4)*4;
  int ocol0 = bn*128 + wn*32 + la;
#pragma unroll
  for (int m = 0; m < 8; ++m)
#pragma unroll
    for (int n = 0; n < 2; ++n)
#pragma unroll
      for (int j = 0; j < 4; ++j)
        C[(size_t)(orow0 + m*16 + j)*NDIM + ocol0 + n*16] = acc[m][n][j];
}

extern "C" void kernel_launch(void* const* d_in, const int* in_sizes, int n_in,
                              void* d_out, int out_size, void* d_ws, size_t ws_size,
                              hipStream_t stream) {
  const float* x = (const float*)d_in[0];
  const float* w = (const float*)d_in[1];
  float* out = (float*)d_out;
  char* ws = (char*)d_ws;
  u16* Bmat = (u16*)(ws + 4096);                             // 2 MB
  u16* Abf  = (u16*)(ws + 4096 + 2*1024*1024);               // 16 MB

  fused_front<<<1536, 256, 0, stream>>>(x, w, Abf, Bmat);
  gemm_bt<<<(BATCH/256)*(NDIM/128), 512, 0, stream>>>(Abf, Bmat, out);
}

// Round 19
// 50.858 us; speedup vs baseline: 1.1554x; 1.1554x over previous
//
#include <hip/hip_runtime.h>
#include <stdint.h>

typedef uint16_t u16;
typedef __attribute__((ext_vector_type(2))) float f32x2;
typedef __attribute__((ext_vector_type(4))) float f32x4;
typedef __attribute__((ext_vector_type(8))) short short8;
typedef __attribute__((ext_vector_type(4))) float float4v;
typedef __attribute__((ext_vector_type(4))) uint16_t u16x4;
typedef __attribute__((ext_vector_type(8))) uint16_t u16x8;

#define DIMQ 1024
#define BATCH 8192
#define KDIM 1024
#define NDIM 1024

#define RDL(v, l) __int_as_float(__builtin_amdgcn_readlane(__float_as_int(v), (l)))

__device__ __forceinline__ u16 f2bf(float f) {
  uint32_t u = __float_as_uint(f);
  u += 0x7fffu + ((u >> 16) & 1u);
  return (u16)(u >> 16);
}

// cross-lane xor exchange; DPP (VALU) for 1,2,8; ds_swizzle for 4,16; shfl for 32.
// (verified R4/R5/R6/R11/R15)
template<int MASK>
__device__ __forceinline__ float lane_xor(float x) {
  if constexpr (MASK == 1)
    return __int_as_float(__builtin_amdgcn_update_dpp(0, __float_as_int(x), 0xB1, 0xF, 0xF, true));
  else if constexpr (MASK == 2)
    return __int_as_float(__builtin_amdgcn_update_dpp(0, __float_as_int(x), 0x4E, 0xF, 0xF, true));
  else if constexpr (MASK == 8)
    return __int_as_float(__builtin_amdgcn_update_dpp(0, __float_as_int(x), 0x128, 0xF, 0xF, true));
  else if constexpr (MASK == 4)
    return __int_as_float(__builtin_amdgcn_ds_swizzle(__float_as_int(x), 0x101F));
  else if constexpr (MASK == 16)
    return __int_as_float(__builtin_amdgcn_ds_swizzle(__float_as_int(x), 0x401F));
  else
    return __shfl_xor(x, 32, 64);
}

// cross-lane gate on 8 regs: batched partner fetch, then PACKED FMAs (verified R14)
template<int MASK>
__device__ __forceinline__ void lane_gate8(float* ar, float* ai, int lane,
    float u00r, float u00i, float u01r, float u01i,
    float u10r, float u10i, float u11r, float u11i) {
  bool hi = (lane & MASK) != 0;
  float cmr = hi ? u11r : u00r, cmi = hi ? u11i : u00i;
  float cor = hi ? u10r : u01r, coi = hi ? u10i : u01i;
  float otr[8], oti[8];
#pragma unroll
  for (int r = 0; r < 8; ++r) otr[r] = lane_xor<MASK>(ar[r]);
#pragma unroll
  for (int r = 0; r < 8; ++r) oti[r] = lane_xor<MASK>(ai[r]);
#pragma unroll
  for (int k = 0; k < 4; ++k) {
    f32x2 A = {ar[2*k], ar[2*k+1]}, I = {ai[2*k], ai[2*k+1]};
    f32x2 R = {otr[2*k], otr[2*k+1]}, J = {oti[2*k], oti[2*k+1]};
    f32x2 nr = A*cmr - I*cmi + R*cor - J*coi;
    f32x2 ni = I*cmr + A*cmi + J*cor + R*coi;
    ar[2*k] = nr[0]; ar[2*k+1] = nr[1];
    ai[2*k] = ni[0]; ai[2*k+1] = ni[1];
  }
}

// packed 2x2 butterfly on two amp pairs at once (verified R14)
__device__ __forceinline__ void bfly2(f32x2 &a0r, f32x2 &a0i, f32x2 &a1r, f32x2 &a1i,
    float u00r, float u00i, float u01r, float u01i,
    float u10r, float u10i, float u11r, float u11i) {
  f32x2 t0r = a0r*u00r - a0i*u00i + a1r*u01r - a1i*u01i;
  f32x2 t0i = a0i*u00r + a0r*u00i + a1i*u01r + a1r*u01i;
  f32x2 t1r = a0r*u10r - a0i*u10i + a1r*u11r - a1i*u11i;
  f32x2 t1i = a0i*u10r + a0r*u10i + a1i*u11r + a1r*u11i;
  a0r = t0r; a0i = t0i; a1r = t1r; a1i = t1i;
}

// complex 2x2 layout: {00r,00i, 01r,01i, 10r,10i, 11r,11i}
__device__ inline void cmul2x2(float* O, const float* A, const float* B) {
  for (int r = 0; r < 2; ++r)
    for (int c = 0; c < 2; ++c) {
      float re = 0.f, im = 0.f;
      for (int j = 0; j < 2; ++j) {
        float ar = A[(r*2+j)*2], ai = A[(r*2+j)*2+1];
        float br = B[(j*2+c)*2], bi = B[(j*2+c)*2+1];
        re += ar*br - ai*bi;
        im += ar*bi + ai*br;
      }
      O[(r*2+c)*2]   = re;
      O[(r*2+c)*2+1] = im;
    }
}
__device__ inline void mk_rx(float* m, float t) {
  float s, c; sincosf(0.5f*t, &s, &c);
  m[0]=c; m[1]=0; m[2]=0; m[3]=-s; m[4]=0; m[5]=-s; m[6]=c; m[7]=0;
}
__device__ inline void mk_ry(float* m, float t) {
  float s, c; sincosf(0.5f*t, &s, &c);
  m[0]=c; m[1]=0; m[2]=-s; m[3]=0; m[4]=s; m[5]=0; m[6]=c; m[7]=0;
}
__device__ inline void mk_rz(float* m, float t) {
  float s, c; sincosf(0.5f*t, &s, &c);
  m[0]=c; m[1]=-s; m[2]=0; m[3]=0; m[4]=0; m[5]=0; m[6]=c; m[7]=s;
}

__device__ __forceinline__ int padi(int y) { return y + (y >> 4); }

// one build stage for stages >= 1 (verified R14): LDS pass (perm + bit-3 gate),
// then in-register gates (bits 2..0), then lane gates (bits 9..4). Packed FMAs.
__device__ __forceinline__ void do_stage(int gbase, float (&ar)[8], float (&ai)[8],
    f32x2* __restrict__ slab,
    const int (&idP0)[8], const int (&idP1)[8],
    int wbase, int lane, int h,
    float O0, float O1, float O2, float O3,
    float O4, float O5, float O6, float O7) {
  __syncthreads();
#pragma unroll
  for (int j = 0; j < 8; ++j) slab[wbase + j] = (f32x2){ar[j], ai[j]};
  __syncthreads();
  {
    int g = gbase + 6;
    float c0r = h ? RDL(O4,g) : RDL(O0,g), c0i = h ? RDL(O5,g) : RDL(O1,g);
    float c1r = h ? RDL(O6,g) : RDL(O2,g), c1i = h ? RDL(O7,g) : RDL(O3,g);
    f32x2 v0[8], v1[8];
#pragma unroll
    for (int j = 0; j < 8; ++j) {
      v0[j] = slab[idP0[j]];
      v1[j] = slab[idP1[j]];
    }
#pragma unroll
    for (int k = 0; k < 4; ++k) {
      f32x2 Vr0 = {v0[2*k][0], v0[2*k+1][0]}, Vi0 = {v0[2*k][1], v0[2*k+1][1]};
      f32x2 Vr1 = {v1[2*k][0], v1[2*k+1][0]}, Vi1 = {v1[2*k][1], v1[2*k+1][1]};
      f32x2 nr = Vr0*c0r - Vi0*c0i + Vr1*c1r - Vi1*c1i;
      f32x2 ni = Vi0*c0r + Vr0*c0i + Vi1*c1r + Vr1*c1i;
      ar[2*k] = nr[0]; ar[2*k+1] = nr[1];
      ai[2*k] = ni[0]; ai[2*k+1] = ni[1];
    }
  }
  { int g = gbase + 7;   // p=2: pairs (r, r+4)
    float u0r=RDL(O0,g),u0i=RDL(O1,g),u1r=RDL(O2,g),u1i=RDL(O3,g);
    float u2r=RDL(O4,g),u2i=RDL(O5,g),u3r=RDL(O6,g),u3i=RDL(O7,g);
    f32x2 a0r={ar[0],ar[1]}, a0i={ai[0],ai[1]}, a1r={ar[4],ar[5]}, a1i={ai[4],ai[5]};
    bfly2(a0r,a0i,a1r,a1i, u0r,u0i,u1r,u1i,u2r,u2i,u3r,u3i);
    ar[0]=a0r[0];ar[1]=a0r[1];ai[0]=a0i[0];ai[1]=a0i[1];
    ar[4]=a1r[0];ar[5]=a1r[1];ai[4]=a1i[0];ai[5]=a1i[1];
    f32x2 b0r={ar[2],ar[3]}, b0i={ai[2],ai[3]}, b1r={ar[6],ar[7]}, b1i={ai[6],ai[7]};
    bfly2(b0r,b0i,b1r,b1i, u0r,u0i,u1r,u1i,u2r,u2i,u3r,u3i);
    ar[2]=b0r[0];ar[3]=b0r[1];ai[2]=b0i[0];ai[3]=b0i[1];
    ar[6]=b1r[0];ar[7]=b1r[1];ai[6]=b1i[0];ai[7]=b1i[1];
  }
  { int g = gbase + 8;   // p=1: pairs (r, r+2)
    float u0r=RDL(O0,g),u0i=RDL(O1,g),u1r=RDL(O2,g),u1i=RDL(O3,g);
    float u2r=RDL(O4,g),u2i=RDL(O5,g),u3r=RDL(O6,g),u3i=RDL(O7,g);
    f32x2 a0r={ar[0],ar[1]}, a0i={ai[0],ai[1]}, a1r={ar[2],ar[3]}, a1i={ai[2],ai[3]};
    bfly2(a0r,a0i,a1r,a1i, u0r,u0i,u1r,u1i,u2r,u2i,u3r,u3i);
    ar[0]=a0r[0];ar[1]=a0r[1];ai[0]=a0i[0];ai[1]=a0i[1];
    ar[2]=a1r[0];ar[3]=a1r[1];ai[2]=a1i[0];ai[3]=a1i[1];
    f32x2 b0r={ar[4],ar[5]}, b0i={ai[4],ai[5]}, b1r={ar[6],ar[7]}, b1i={ai[6],ai[7]};
    bfly2(b0r,b0i,b1r,b1i, u0r,u0i,u1r,u1i,u2r,u2i,u3r,u3i);
    ar[4]=b0r[0];ar[5]=b0r[1];ai[4]=b0i[0];ai[5]=b0i[1];
    ar[6]=b1r[0];ar[7]=b1r[1];ai[6]=b1i[0];ai[7]=b1i[1];
  }
  { int g = gbase + 9;   // p=0: pairs (r, r+1), packed along bit 1
    float u0r=RDL(O0,g),u0i=RDL(O1,g),u1r=RDL(O2,g),u1i=RDL(O3,g);
    float u2r=RDL(O4,g),u2i=RDL(O5,g),u3r=RDL(O6,g),u3i=RDL(O7,g);
    f32x2 a0r={ar[0],ar[2]}, a0i={ai[0],ai[2]}, a1r={ar[1],ar[3]}, a1i={ai[1],ai[3]};
    bfly2(a0r,a0i,a1r,a1i, u0r,u0i,u1r,u1i,u2r,u2i,u3r,u3i);
    ar[0]=a0r[0];ar[2]=a0r[1];ai[0]=a0i[0];ai[2]=a0i[1];
    ar[1]=a1r[0];ar[3]=a1r[1];ai[1]=a1i[0];ai[3]=a1i[1];
    f32x2 b0r={ar[4],ar[6]}, b0i={ai[4],ai[6]}, b1r={ar[5],ar[7]}, b1i={ai[5],ai[7]};
    bfly2(b0r,b0i,b1r,b1i, u0r,u0i,u1r,u1i,u2r,u2i,u3r,u3i);
    ar[4]=b0r[0];ar[6]=b0r[1];ai[4]=b0i[0];ai[6]=b0i[1];
    ar[5]=b1r[0];ar[7]=b1r[1];ai[5]=b1i[0];ai[7]=b1i[1];
  }
  { int g = gbase + 0; lane_gate8<32>(ar, ai, lane, RDL(O0,g),RDL(O1,g),RDL(O2,g),RDL(O3,g),RDL(O4,g),RDL(O5,g),RDL(O6,g),RDL(O7,g)); }
  { int g = gbase + 1; lane_gate8<16>(ar, ai, lane, RDL(O0,g),RDL(O1,g),RDL(O2,g),RDL(O3,g),RDL(O4,g),RDL(O5,g),RDL(O6,g),RDL(O7,g)); }
  { int g = gbase + 2; lane_gate8< 8>(ar, ai, lane, RDL(O0,g),RDL(O1,g),RDL(O2,g),RDL(O3,g),RDL(O4,g),RDL(O5,g),RDL(O6,g),RDL(O7,g)); }
  { int g = gbase + 3; lane_gate8< 4>(ar, ai, lane, RDL(O0,g),RDL(O1,g),RDL(O2,g),RDL(O3,g),RDL(O4,g),RDL(O5,g),RDL(O6,g),RDL(O7,g)); }
  { int g = gbase + 4; lane_gate8< 2>(ar, ai, lane, RDL(O0,g),RDL(O1,g),RDL(O2,g),RDL(O3,g),RDL(O4,g),RDL(O5,g),RDL(O6,g),RDL(O7,g)); }
  { int g = gbase + 5; lane_gate8< 1>(ar, ai, lane, RDL(O0,g),RDL(O1,g),RDL(O2,g),RDL(O3,g),RDL(O4,g),RDL(O5,g),RDL(O6,g),RDL(O7,g)); }
}

// Fused front (R15/R17 exact).
__global__ __launch_bounds__(256) void fused_front(const float* __restrict__ x,
                                                   const float* __restrict__ w,
                                                   u16* __restrict__ Abf,
                                                   u16* __restrict__ Bmat) {
  __shared__ f32x2 slab[2][1088];
  const int bid = blockIdx.x;
  const int lane = threadIdx.x & 63, wv = threadIdx.x >> 6;

  if (bid >= 512) {
    int base = (bid - 512) * 16 + wv * 4;
    for (int it = 0; it < 4; ++it) {
      int row = base + it;
      const float* xr = x + (size_t)row * DIMQ;
      float4v v[4];
      float ss = 0.f;
#pragma unroll
      for (int j = 0; j < 4; ++j) {
        v[j] = *(const float4v*)(xr + j*256 + lane*4);
        ss += v[j][0]*v[j][0] + v[j][1]*v[j][1] + v[j][2]*v[j][2] + v[j][3]*v[j][3];
      }
#pragma unroll
      for (int off = 32; off; off >>= 1) ss += __shfl_xor(ss, off, 64);
      float inv = 1.0f / fmaxf(sqrtf(ss), 1e-12f);
      u16* orow = Abf + (size_t)row * DIMQ;
#pragma unroll
      for (int j = 0; j < 4; ++j) {
        u16x4 o;
#pragma unroll
        for (int e = 0; e < 4; ++e) o[e] = f2bf(v[j][e] * inv);
        *(u16x4*)(orow + j*256 + lane*4) = o;
      }
    }
    return;
  }

  const int s = wv >> 1, h = wv & 1;
  const int d = bid * 2 + s;

  float O0, O1, O2, O3, O4, O5, O6, O7;
  {
    float A[8], B[8], C[8], T8[8], O[8];
    int t = lane;
    if (t < 50) {
      if (t < 10) {
        mk_ry(A, -w[120 + t]);
        mk_rz(B, -w[130 + t]);
        mk_ry(C, -w[140 + t]);
      } else {
        int sg = (t - 10) / 10, q = (t - 10) % 10, l = 3 - sg;
        mk_rx(A, -w[l*30 + q]);
        mk_ry(B, -w[l*30 + 10 + q]);
        mk_rz(C, -w[l*30 + 20 + q]);
      }
      cmul2x2(T8, A, B);
      cmul2x2(O, T8, C);
    } else {
#pragma unroll
      for (int j = 0; j < 8; ++j) O[j] = 0.f;
    }
    O0=O[0]; O1=O[1]; O2=O[2]; O3=O[3]; O4=O[4]; O5=O[5]; O6=O[6]; O7=O[7];
  }

  int idP0[8], idP1[8];
  int s8;
  {
    int yy = 8;
#pragma unroll
    for (int qq = 0; qq < 9; ++qq) yy ^= ((yy >> (9 - qq)) & 1) << (8 - qq);
    yy ^= (yy & 1) << 9;
    s8 = yy;
  }
#pragma unroll
  for (int j = 0; j < 8; ++j) {
    int xx = (lane << 4) + j;
    int yy = xx;
#pragma unroll
    for (int qq = 0; qq < 9; ++qq) yy ^= ((yy >> (9 - qq)) & 1) << (8 - qq);
    yy ^= (yy & 1) << 9;
    idP0[j] = padi(yy);
    idP1[j] = padi(yy ^ s8);
  }
  const int wbase = lane * 17 + h * 8;

  float ar[8], ai[8];
  {
    float fr = 1.0f, fi = 0.0f;
#pragma unroll
    for (int p = 4; p <= 9; ++p) {
      const int q = 9 - p;
      int c = (d >> p) & 1;
      float a0r = c ? RDL(O2,q) : RDL(O0,q), a0i = c ? RDL(O3,q) : RDL(O1,q);
      float a1r = c ? RDL(O6,q) : RDL(O4,q), a1i = c ? RDL(O7,q) : RDL(O5,q);
      bool hb = (lane >> (p - 4)) & 1;
      float gr = hb ? a1r : a0r, gi = hb ? a1i : a0i;
      float nr = fr*gr - fi*gi, ni = fr*gi + fi*gr;
      fr = nr; fi = ni;
    }
    {
      int c = (d >> 3) & 1;
      float a0r = c ? RDL(O2,6) : RDL(O0,6), a0i = c ? RDL(O3,6) : RDL(O1,6);
      float a1r = c ? RDL(O6,6) : RDL(O4,6), a1i = c ? RDL(O7,6) : RDL(O5,6);
      float gr = h ? a1r : a0r, gi = h ? a1i : a0i;
      float nr = fr*gr - fi*gi, ni = fr*gi + fi*gr;
      fr = nr; fi = ni;
    }
    float t2r[2], t2i[2], t1r[2], t1i[2], t0r[2], t0i[2];
    {
      int c = (d >> 2) & 1;
      t2r[0] = c ? RDL(O2,7) : RDL(O0,7); t2i[0] = c ? RDL(O3,7) : RDL(O1,7);
      t2r[1] = c ? RDL(O6,7) : RDL(O4,7); t2i[1] = c ? RDL(O7,7) : RDL(O5,7);
    }
    {
      int c = (d >> 1) & 1;
      t1r[0] = c ? RDL(O2,8) : RDL(O0,8); t1i[0] = c ? RDL(O3,8) : RDL(O1,8);
      t1r[1] = c ? RDL(O6,8) : RDL(O4,8); t1i[1] = c ? RDL(O7,8) : RDL(O5,8);
    }
    {
      int c = d & 1;
      t0r[0] = c ? RDL(O2,9) : RDL(O0,9); t0i[0] = c ? RDL(O3,9) : RDL(O1,9);
      t0r[1] = c ? RDL(O6,9) : RDL(O4,9); t0i[1] = c ? RDL(O7,9) : RDL(O5,9);
    }
    float m21r[4], m21i[4];
#pragma unroll
    for (int b2 = 0; b2 < 2; ++b2)
#pragma unroll
      for (int b1 = 0; b1 < 2; ++b1) {
        m21r[b2*2+b1] = t2r[b2]*t1r[b1] - t2i[b2]*t1i[b1];
        m21i[b2*2+b1] = t2r[b2]*t1i[b1] + t2i[b2]*t1r[b1];
      }
#pragma unroll
    for (int j = 0; j < 8; ++j) {
      int hi2 = j >> 1;
      int b0 = j & 1;
      float wr = m21r[hi2]*t0r[b0] - m21i[hi2]*t0i[b0];
      float wi = m21r[hi2]*t0i[b0] + m21i[hi2]*t0r[b0];
      ar[j] = fr*wr - fi*wi;
      ai[j] = fr*wi + fi*wr;
    }
  }

#pragma clang loop unroll(disable)
  for (int stage = 1; stage < 5; ++stage)
    do_stage(stage*10, ar, ai, slab[s], idP0, idP1, wbase, lane, h,
             O0,O1,O2,O3,O4,O5,O6,O7);

  u16x8 o;
#pragma unroll
  for (int j = 0; j < 8; ++j) o[j] = f2bf(ar[j]);
  *(u16x8*)(Bmat + (size_t)d * DIMQ + lane*16 + h*8) = o;
}

// C[8192,1024] = A * B^T  (bf16 in, fp32 out)
// BM=256 x BN=128, BK=64, 512 threads, THREE LDS buffers (144 KB),
// T3+T4: 2-deep prefetch with COUNTED vmcnt(6) (never drain mid-loop),
// raw s_barrier (no compiler vmcnt-0 drain), both-sides swizzle, T5 setprio.
// Safety: reads of tile kt-1 complete before iter-kt barrier; iter-kt stage
// targets buffer (kt+2)%3 which holds kt-1 -> no wave can still be reading it.
__global__ __launch_bounds__(512) void gemm_bt(const u16* __restrict__ A,
                                               const u16* __restrict__ Bm,
                                               float* __restrict__ C) {
  __shared__ u16 As[3][256*64];
  __shared__ u16 Bs[3][128*64];
  const int t = threadIdx.x, lane = t & 63, wave = t >> 6;
  int bid = blockIdx.x;
  int nid = ((bid & 7) << 5) | (bid >> 3);
  const int bm = nid >> 3, bn = nid & 7;
  const size_t aBase = (size_t)bm * 256 * KDIM;
  const size_t bBase = (size_t)bn * 128 * KDIM;

  const int srow = t >> 3;
  const int scol = ((t & 7) ^ (srow & 7)) * 8;
  const int dstB = srow * 128 + (t & 7) * 16;

  const int wm = wave >> 2, wn = wave & 3;
  const int la = lane & 15;
  const int lkB = ((lane >> 4) * 16);
  const int rsw = (lane & 7) << 4;

  f32x4 acc[8][2];
#pragma unroll
  for (int m = 0; m < 8; ++m)
#pragma unroll
    for (int n = 0; n < 2; ++n) acc[m][n] = (f32x4){0.f, 0.f, 0.f, 0.f};

  auto stage = [&](int b, int kt) {
    int k0 = kt * 64;
#pragma unroll
    for (int j = 0; j < 4; ++j) {
      __builtin_amdgcn_global_load_lds(
          (const __attribute__((address_space(1))) void*)(A + aBase + (size_t)(j*64 + srow)*KDIM + k0 + scol),
          (__attribute__((address_space(3))) void*)((char*)&As[b][0] + j*8192 + dstB), 16, 0, 0);
    }
#pragma unroll
    for (int j = 0; j < 2; ++j) {
      __builtin_amdgcn_global_load_lds(
          (const __attribute__((address_space(1))) void*)(Bm + bBase + (size_t)(j*64 + srow)*KDIM + k0 + scol),
          (__attribute__((address_space(3))) void*)((char*)&Bs[b][0] + j*8192 + dstB), 16, 0, 0);
    }
  };

  stage(0, 0);
  stage(1, 1);

#pragma clang loop unroll(disable)
  for (int kt = 0; kt < 16; ++kt) {
    const int cur = kt % 3;
    // wait for tile kt's 6 loads; tile kt+1's 6 may stay in flight
    if (kt < 15)
      asm volatile("s_waitcnt vmcnt(6)" ::: "memory");
    else
      asm volatile("s_waitcnt vmcnt(0)" ::: "memory");
    __builtin_amdgcn_s_barrier();      // raw: no compiler drain
    short8 af[8][2], bf[2][2];
#pragma unroll
    for (int kk = 0; kk < 2; ++kk) {
#pragma unroll
      for (int m = 0; m < 8; ++m) {
        int row = wm*128 + m*16 + la;
        int byt = (row*128 + kk*64 + lkB) ^ rsw;
        af[m][kk] = *(const short8*)((char*)&As[cur][0] + byt);
      }
#pragma unroll
      for (int n = 0; n < 2; ++n) {
        int row = wn*32 + n*16 + la;
        int byt = (row*128 + kk*64 + lkB) ^ rsw;
        bf[n][kk] = *(const short8*)((char*)&Bs[cur][0] + byt);
      }
    }
    if (kt < 14) stage((kt + 2) % 3, kt + 2);   // overwrite buffer of tile kt-1
    __builtin_amdgcn_s_setprio(1);
#pragma unroll
    for (int kk = 0; kk < 2; ++kk)
#pragma unroll
      for (int m = 0; m < 8; ++m)
#pragma unroll
        for (int n = 0; n < 2; ++n)
          acc[m][n] = __builtin_amdgcn_mfma_f32_16x16x32_bf16(af[m][kk], bf[n][kk], acc[m][n], 0, 0, 0);
    __builtin_amdgcn_s_setprio(0);
  }

  int orow0 = bm*256 + wm*128 + (lane >> 4)*4;
  int ocol0 = bn*128 + wn*32 + la;
#pragma unroll
  for (int m = 0; m < 8; ++m)
#pragma unroll
    for (int n = 0; n < 2; ++n)
#pragma unroll
      for (int j = 0; j < 4; ++j)
        C[(size_t)(orow0 + m*16 + j)*NDIM + ocol0 + n*16] = acc[m][n][j];
}

extern "C" void kernel_launch(void* const* d_in, const int* in_sizes, int n_in,
                              void* d_out, int out_size, void* d_ws, size_t ws_size,
                              hipStream_t stream) {
  const float* x = (const float*)d_in[0];
  const float* w = (const float*)d_in[1];
  float* out = (float*)d_out;
  char* ws = (char*)d_ws;
  u16* Bmat = (u16*)(ws + 4096);                             // 2 MB
  u16* Abf  = (u16*)(ws + 4096 + 2*1024*1024);               // 16 MB

  fused_front<<<1024, 256, 0, stream>>>(x, w, Abf, Bmat);
  gemm_bt<<<(BATCH/256)*(NDIM/128), 512, 0, stream>>>(Abf, Bmat, out);
}

// Round 20
// 49.586 us; speedup vs baseline: 1.1850x; 1.0256x over previous
//
#include <hip/hip_runtime.h>
#include <stdint.h>

typedef uint16_t u16;
typedef __attribute__((ext_vector_type(2))) float f32x2;
typedef __attribute__((ext_vector_type(4))) float f32x4;
typedef __attribute__((ext_vector_type(8))) short short8;
typedef __attribute__((ext_vector_type(4))) float float4v;
typedef __attribute__((ext_vector_type(4))) uint16_t u16x4;
typedef __attribute__((ext_vector_type(8))) uint16_t u16x8;

#define DIMQ 1024
#define BATCH 8192
#define KDIM 1024
#define NDIM 1024

#define RDL(v, l) __int_as_float(__builtin_amdgcn_readlane(__float_as_int(v), (l)))

__device__ __forceinline__ u16 f2bf(float f) {
  uint32_t u = __float_as_uint(f);
  u += 0x7fffu + ((u >> 16) & 1u);
  return (u16)(u >> 16);
}

// cross-lane xor exchange; DPP (VALU) for 1,2,8; ds_swizzle for 4,16; shfl for 32.
// (verified R4/R5/R6/R11/R15)
template<int MASK>
__device__ __forceinline__ float lane_xor(float x) {
  if constexpr (MASK == 1)
    return __int_as_float(__builtin_amdgcn_update_dpp(0, __float_as_int(x), 0xB1, 0xF, 0xF, true));
  else if constexpr (MASK == 2)
    return __int_as_float(__builtin_amdgcn_update_dpp(0, __float_as_int(x), 0x4E, 0xF, 0xF, true));
  else if constexpr (MASK == 8)
    return __int_as_float(__builtin_amdgcn_update_dpp(0, __float_as_int(x), 0x128, 0xF, 0xF, true));
  else if constexpr (MASK == 4)
    return __int_as_float(__builtin_amdgcn_ds_swizzle(__float_as_int(x), 0x101F));
  else if constexpr (MASK == 16)
    return __int_as_float(__builtin_amdgcn_ds_swizzle(__float_as_int(x), 0x401F));
  else
    return __shfl_xor(x, 32, 64);
}

// cross-lane gate on 8 regs: batched partner fetch, then PACKED FMAs (verified R14)
template<int MASK>
__device__ __forceinline__ void lane_gate8(float* ar, float* ai, int lane,
    float u00r, float u00i, float u01r, float u01i,
    float u10r, float u10i, float u11r, float u11i) {
  bool hi = (lane & MASK) != 0;
  float cmr = hi ? u11r : u00r, cmi = hi ? u11i : u00i;
  float cor = hi ? u10r : u01r, coi = hi ? u10i : u01i;
  float otr[8], oti[8];
#pragma unroll
  for (int r = 0; r < 8; ++r) otr[r] = lane_xor<MASK>(ar[r]);
#pragma unroll
  for (int r = 0; r < 8; ++r) oti[r] = lane_xor<MASK>(ai[r]);
#pragma unroll
  for (int k = 0; k < 4; ++k) {
    f32x2 A = {ar[2*k], ar[2*k+1]}, I = {ai[2*k], ai[2*k+1]};
    f32x2 R = {otr[2*k], otr[2*k+1]}, J = {oti[2*k], oti[2*k+1]};
    f32x2 nr = A*cmr - I*cmi + R*cor - J*coi;
    f32x2 ni = I*cmr + A*cmi + J*cor + R*coi;
    ar[2*k] = nr[0]; ar[2*k+1] = nr[1];
    ai[2*k] = ni[0]; ai[2*k+1] = ni[1];
  }
}

// packed 2x2 butterfly on two amp pairs at once (verified R14)
__device__ __forceinline__ void bfly2(f32x2 &a0r, f32x2 &a0i, f32x2 &a1r, f32x2 &a1i,
    float u00r, float u00i, float u01r, float u01i,
    float u10r, float u10i, float u11r, float u11i) {
  f32x2 t0r = a0r*u00r - a0i*u00i + a1r*u01r - a1i*u01i;
  f32x2 t0i = a0i*u00r + a0r*u00i + a1i*u01r + a1r*u01i;
  f32x2 t1r = a0r*u10r - a0i*u10i + a1r*u11r - a1i*u11i;
  f32x2 t1i = a0i*u10r + a0r*u10i + a1i*u11r + a1r*u11i;
  a0r = t0r; a0i = t0i; a1r = t1r; a1i = t1i;
}

// complex 2x2 layout: {00r,00i, 01r,01i, 10r,10i, 11r,11i}
__device__ inline void cmul2x2(float* O, const float* A, const float* B) {
  for (int r = 0; r < 2; ++r)
    for (int c = 0; c < 2; ++c) {
      float re = 0.f, im = 0.f;
      for (int j = 0; j < 2; ++j) {
        float ar = A[(r*2+j)*2], ai = A[(r*2+j)*2+1];
        float br = B[(j*2+c)*2], bi = B[(j*2+c)*2+1];
        re += ar*br - ai*bi;
        im += ar*bi + ai*br;
      }
      O[(r*2+c)*2]   = re;
      O[(r*2+c)*2+1] = im;
    }
}
__device__ inline void mk_rx(float* m, float t) {
  float s, c; sincosf(0.5f*t, &s, &c);
  m[0]=c; m[1]=0; m[2]=0; m[3]=-s; m[4]=0; m[5]=-s; m[6]=c; m[7]=0;
}
__device__ inline void mk_ry(float* m, float t) {
  float s, c; sincosf(0.5f*t, &s, &c);
  m[0]=c; m[1]=0; m[2]=-s; m[3]=0; m[4]=s; m[5]=0; m[6]=c; m[7]=0;
}
__device__ inline void mk_rz(float* m, float t) {
  float s, c; sincosf(0.5f*t, &s, &c);
  m[0]=c; m[1]=-s; m[2]=0; m[3]=0; m[4]=0; m[5]=0; m[6]=c; m[7]=s;
}

__device__ __forceinline__ int padi(int y) { return y + (y >> 4); }

// one build stage (R14 verified math). ONE barrier per stage: the slab is
// double-buffered by stage parity, so the pre-write guard barrier is gone
// (stage s+1 writes buffer p^1 while any straggler still reads buffer p).
__device__ __forceinline__ void do_stage(int gbase, float (&ar)[8], float (&ai)[8],
    f32x2* __restrict__ slab,
    const int (&idP0)[8], const int (&idP1)[8],
    int wbase, int lane, int h,
    float O0, float O1, float O2, float O3,
    float O4, float O5, float O6, float O7) {
#pragma unroll
  for (int j = 0; j < 8; ++j) slab[wbase + j] = (f32x2){ar[j], ai[j]};
  __syncthreads();
  {
    int g = gbase + 6;
    float c0r = h ? RDL(O4,g) : RDL(O0,g), c0i = h ? RDL(O5,g) : RDL(O1,g);
    float c1r = h ? RDL(O6,g) : RDL(O2,g), c1i = h ? RDL(O7,g) : RDL(O3,g);
    f32x2 v0[8], v1[8];
#pragma unroll
    for (int j = 0; j < 8; ++j) {
      v0[j] = slab[idP0[j]];
      v1[j] = slab[idP1[j]];
    }
#pragma unroll
    for (int k = 0; k < 4; ++k) {
      f32x2 Vr0 = {v0[2*k][0], v0[2*k+1][0]}, Vi0 = {v0[2*k][1], v0[2*k+1][1]};
      f32x2 Vr1 = {v1[2*k][0], v1[2*k+1][0]}, Vi1 = {v1[2*k][1], v1[2*k+1][1]};
      f32x2 nr = Vr0*c0r - Vi0*c0i + Vr1*c1r - Vi1*c1i;
      f32x2 ni = Vi0*c0r + Vr0*c0i + Vi1*c1r + Vr1*c1i;
      ar[2*k] = nr[0]; ar[2*k+1] = nr[1];
      ai[2*k] = ni[0]; ai[2*k+1] = ni[1];
    }
  }
  { int g = gbase + 7;   // p=2: pairs (r, r+4)
    float u0r=RDL(O0,g),u0i=RDL(O1,g),u1r=RDL(O2,g),u1i=RDL(O3,g);
    float u2r=RDL(O4,g),u2i=RDL(O5,g),u3r=RDL(O6,g),u3i=RDL(O7,g);
    f32x2 a0r={ar[0],ar[1]}, a0i={ai[0],ai[1]}, a1r={ar[4],ar[5]}, a1i={ai[4],ai[5]};
    bfly2(a0r,a0i,a1r,a1i, u0r,u0i,u1r,u1i,u2r,u2i,u3r,u3i);
    ar[0]=a0r[0];ar[1]=a0r[1];ai[0]=a0i[0];ai[1]=a0i[1];
    ar[4]=a1r[0];ar[5]=a1r[1];ai[4]=a1i[0];ai[5]=a1i[1];
    f32x2 b0r={ar[2],ar[3]}, b0i={ai[2],ai[3]}, b1r={ar[6],ar[7]}, b1i={ai[6],ai[7]};
    bfly2(b0r,b0i,b1r,b1i, u0r,u0i,u1r,u1i,u2r,u2i,u3r,u3i);
    ar[2]=b0r[0];ar[3]=b0r[1];ai[2]=b0i[0];ai[3]=b0i[1];
    ar[6]=b1r[0];ar[7]=b1r[1];ai[6]=b1i[0];ai[7]=b1i[1];
  }
  { int g = gbase + 8;   // p=1: pairs (r, r+2)
    float u0r=RDL(O0,g),u0i=RDL(O1,g),u1r=RDL(O2,g),u1i=RDL(O3,g);
    float u2r=RDL(O4,g),u2i=RDL(O5,g),u3r=RDL(O6,g),u3i=RDL(O7,g);
    f32x2 a0r={ar[0],ar[1]}, a0i={ai[0],ai[1]}, a1r={ar[2],ar[3]}, a1i={ai[2],ai[3]};
    bfly2(a0r,a0i,a1r,a1i, u0r,u0i,u1r,u1i,u2r,u2i,u3r,u3i);
    ar[0]=a0r[0];ar[1]=a0r[1];ai[0]=a0i[0];ai[1]=a0i[1];
    ar[2]=a1r[0];ar[3]=a1r[1];ai[2]=a1i[0];ai[3]=a1i[1];
    f32x2 b0r={ar[4],ar[5]}, b0i={ai[4],ai[5]}, b1r={ar[6],ar[7]}, b1i={ai[6],ai[7]};
    bfly2(b0r,b0i,b1r,b1i, u0r,u0i,u1r,u1i,u2r,u2i,u3r,u3i);
    ar[4]=b0r[0];ar[5]=b0r[1];ai[4]=b0i[0];ai[5]=b0i[1];
    ar[6]=b1r[0];ar[7]=b1r[1];ai[6]=b1i[0];ai[7]=b1i[1];
  }
  { int g = gbase + 9;   // p=0: pairs (r, r+1), packed along bit 1
    float u0r=RDL(O0,g),u0i=RDL(O1,g),u1r=RDL(O2,g),u1i=RDL(O3,g);
    float u2r=RDL(O4,g),u2i=RDL(O5,g),u3r=RDL(O6,g),u3i=RDL(O7,g);
    f32x2 a0r={ar[0],ar[2]}, a0i={ai[0],ai[2]}, a1r={ar[1],ar[3]}, a1i={ai[1],ai[3]};
    bfly2(a0r,a0i,a1r,a1i, u0r,u0i,u1r,u1i,u2r,u2i,u3r,u3i);
    ar[0]=a0r[0];ar[2]=a0r[1];ai[0]=a0i[0];ai[2]=a0i[1];
    ar[1]=a1r[0];ar[3]=a1r[1];ai[1]=a1i[0];ai[3]=a1i[1];
    f32x2 b0r={ar[4],ar[6]}, b0i={ai[4],ai[6]}, b1r={ar[5],ar[7]}, b1i={ai[5],ai[7]};
    bfly2(b0r,b0i,b1r,b1i, u0r,u0i,u1r,u1i,u2r,u2i,u3r,u3i);
    ar[4]=b0r[0];ar[6]=b0r[1];ai[4]=b0i[0];ai[6]=b0i[1];
    ar[5]=b1r[0];ar[7]=b1r[1];ai[5]=b1i[0];ai[7]=b1i[1];
  }
  { int g = gbase + 0; lane_gate8<32>(ar, ai, lane, RDL(O0,g),RDL(O1,g),RDL(O2,g),RDL(O3,g),RDL(O4,g),RDL(O5,g),RDL(O6,g),RDL(O7,g)); }
  { int g = gbase + 1; lane_gate8<16>(ar, ai, lane, RDL(O0,g),RDL(O1,g),RDL(O2,g),RDL(O3,g),RDL(O4,g),RDL(O5,g),RDL(O6,g),RDL(O7,g)); }
  { int g = gbase + 2; lane_gate8< 8>(ar, ai, lane, RDL(O0,g),RDL(O1,g),RDL(O2,g),RDL(O3,g),RDL(O4,g),RDL(O5,g),RDL(O6,g),RDL(O7,g)); }
  { int g = gbase + 3; lane_gate8< 4>(ar, ai, lane, RDL(O0,g),RDL(O1,g),RDL(O2,g),RDL(O3,g),RDL(O4,g),RDL(O5,g),RDL(O6,g),RDL(O7,g)); }
  { int g = gbase + 4; lane_gate8< 2>(ar, ai, lane, RDL(O0,g),RDL(O1,g),RDL(O2,g),RDL(O3,g),RDL(O4,g),RDL(O5,g),RDL(O6,g),RDL(O7,g)); }
  { int g = gbase + 5; lane_gate8< 1>(ar, ai, lane, RDL(O0,g),RDL(O1,g),RDL(O2,g),RDL(O3,g),RDL(O4,g),RDL(O5,g),RDL(O6,g),RDL(O7,g)); }
}

// Fused front (R15 math; slab double-buffered by stage parity).
//   blocks [0, 512):     build — states d0=2*bid (waves 0,1), d1=2*bid+1 (waves 2,3).
//   blocks [512, 1024):  row-normalize x -> bf16, 16 rows per block.
__global__ __launch_bounds__(256) void fused_front(const float* __restrict__ x,
                                                   const float* __restrict__ w,
                                                   u16* __restrict__ Abf,
                                                   u16* __restrict__ Bmat) {
  __shared__ f32x2 slab[2][2][1088];   // [state][stage parity][padded 1024]
  const int bid = blockIdx.x;
  const int lane = threadIdx.x & 63, wv = threadIdx.x >> 6;

  if (bid >= 512) {
    int base = (bid - 512) * 16 + wv * 4;
    for (int it = 0; it < 4; ++it) {
      int row = base + it;
      const float* xr = x + (size_t)row * DIMQ;
      float4v v[4];
      float ss = 0.f;
#pragma unroll
      for (int j = 0; j < 4; ++j) {
        v[j] = *(const float4v*)(xr + j*256 + lane*4);
        ss += v[j][0]*v[j][0] + v[j][1]*v[j][1] + v[j][2]*v[j][2] + v[j][3]*v[j][3];
      }
#pragma unroll
      for (int off = 32; off; off >>= 1) ss += __shfl_xor(ss, off, 64);
      float inv = 1.0f / fmaxf(sqrtf(ss), 1e-12f);
      u16* orow = Abf + (size_t)row * DIMQ;
#pragma unroll
      for (int j = 0; j < 4; ++j) {
        u16x4 o;
#pragma unroll
        for (int e = 0; e < 4; ++e) o[e] = f2bf(v[j][e] * inv);
        *(u16x4*)(orow + j*256 + lane*4) = o;
      }
    }
    return;
  }

  const int s = wv >> 1, h = wv & 1;
  const int d = bid * 2 + s;

  float O0, O1, O2, O3, O4, O5, O6, O7;
  {
    float A[8], B[8], C[8], T8[8], O[8];
    int t = lane;
    if (t < 50) {
      if (t < 10) {
        mk_ry(A, -w[120 + t]);
        mk_rz(B, -w[130 + t]);
        mk_ry(C, -w[140 + t]);
      } else {
        int sg = (t - 10) / 10, q = (t - 10) % 10, l = 3 - sg;
        mk_rx(A, -w[l*30 + q]);
        mk_ry(B, -w[l*30 + 10 + q]);
        mk_rz(C, -w[l*30 + 20 + q]);
      }
      cmul2x2(T8, A, B);
      cmul2x2(O, T8, C);
    } else {
#pragma unroll
      for (int j = 0; j < 8; ++j) O[j] = 0.f;
    }
    O0=O[0]; O1=O[1]; O2=O[2]; O3=O[3]; O4=O[4]; O5=O[5]; O6=O[6]; O7=O[7];
  }

  int idP0[8], idP1[8];
  int s8;
  {
    int yy = 8;
#pragma unroll
    for (int qq = 0; qq < 9; ++qq) yy ^= ((yy >> (9 - qq)) & 1) << (8 - qq);
    yy ^= (yy & 1) << 9;
    s8 = yy;
  }
#pragma unroll
  for (int j = 0; j < 8; ++j) {
    int xx = (lane << 4) + j;
    int yy = xx;
#pragma unroll
    for (int qq = 0; qq < 9; ++qq) yy ^= ((yy >> (9 - qq)) & 1) << (8 - qq);
    yy ^= (yy & 1) << 9;
    idP0[j] = padi(yy);
    idP1[j] = padi(yy ^ s8);
  }
  const int wbase = lane * 17 + h * 8;

  float ar[8], ai[8];
  {
    float fr = 1.0f, fi = 0.0f;
#pragma unroll
    for (int p = 4; p <= 9; ++p) {
      const int q = 9 - p;
      int c = (d >> p) & 1;
      float a0r = c ? RDL(O2,q) : RDL(O0,q), a0i = c ? RDL(O3,q) : RDL(O1,q);
      float a1r = c ? RDL(O6,q) : RDL(O4,q), a1i = c ? RDL(O7,q) : RDL(O5,q);
      bool hb = (lane >> (p - 4)) & 1;
      float gr = hb ? a1r : a0r, gi = hb ? a1i : a0i;
      float nr = fr*gr - fi*gi, ni = fr*gi + fi*gr;
      fr = nr; fi = ni;
    }
    {
      int c = (d >> 3) & 1;
      float a0r = c ? RDL(O2,6) : RDL(O0,6), a0i = c ? RDL(O3,6) : RDL(O1,6);
      float a1r = c ? RDL(O6,6) : RDL(O4,6), a1i = c ? RDL(O7,6) : RDL(O5,6);
      float gr = h ? a1r : a0r, gi = h ? a1i : a0i;
      float nr = fr*gr - fi*gi, ni = fr*gi + fi*gr;
      fr = nr; fi = ni;
    }
    float t2r[2], t2i[2], t1r[2], t1i[2], t0r[2], t0i[2];
    {
      int c = (d >> 2) & 1;
      t2r[0] = c ? RDL(O2,7) : RDL(O0,7); t2i[0] = c ? RDL(O3,7) : RDL(O1,7);
      t2r[1] = c ? RDL(O6,7) : RDL(O4,7); t2i[1] = c ? RDL(O7,7) : RDL(O5,7);
    }
    {
      int c = (d >> 1) & 1;
      t1r[0] = c ? RDL(O2,8) : RDL(O0,8); t1i[0] = c ? RDL(O3,8) : RDL(O1,8);
      t1r[1] = c ? RDL(O6,8) : RDL(O4,8); t1i[1] = c ? RDL(O7,8) : RDL(O5,8);
    }
    {
      int c = d & 1;
      t0r[0] = c ? RDL(O2,9) : RDL(O0,9); t0i[0] = c ? RDL(O3,9) : RDL(O1,9);
      t0r[1] = c ? RDL(O6,9) : RDL(O4,9); t0i[1] = c ? RDL(O7,9) : RDL(O5,9);
    }
    float m21r[4], m21i[4];
#pragma unroll
    for (int b2 = 0; b2 < 2; ++b2)
#pragma unroll
      for (int b1 = 0; b1 < 2; ++b1) {
        m21r[b2*2+b1] = t2r[b2]*t1r[b1] - t2i[b2]*t1i[b1];
        m21i[b2*2+b1] = t2r[b2]*t1i[b1] + t2i[b2]*t1r[b1];
      }
#pragma unroll
    for (int j = 0; j < 8; ++j) {
      int hi2 = j >> 1;
      int b0 = j & 1;
      float wr = m21r[hi2]*t0r[b0] - m21i[hi2]*t0i[b0];
      float wi = m21r[hi2]*t0i[b0] + m21i[hi2]*t0r[b0];
      ar[j] = fr*wr - fi*wi;
      ai[j] = fr*wi + fi*wr;
    }
  }

  // stages 1..4, slab parity alternates (one barrier per stage)
  do_stage(10, ar, ai, slab[s][0], idP0, idP1, wbase, lane, h, O0,O1,O2,O3,O4,O5,O6,O7);
  do_stage(20, ar, ai, slab[s][1], idP0, idP1, wbase, lane, h, O0,O1,O2,O3,O4,O5,O6,O7);
  do_stage(30, ar, ai, slab[s][0], idP0, idP1, wbase, lane, h, O0,O1,O2,O3,O4,O5,O6,O7);
  do_stage(40, ar, ai, slab[s][1], idP0, idP1, wbase, lane, h, O0,O1,O2,O3,O4,O5,O6,O7);

  u16x8 o;
#pragma unroll
  for (int j = 0; j < 8; ++j) o[j] = f2bf(ar[j]);
  *(u16x8*)(Bmat + (size_t)d * DIMQ + lane*16 + h*8) = o;
}

// C[8192,1024] = A * B^T  (bf16 in, fp32 out) — R19 verified.
// BM=256 x BN=128, BK=64, 512 threads, 3 LDS buffers, counted vmcnt(6),
// raw s_barrier, both-sides swizzle, T5 setprio.
__global__ __launch_bounds__(512) void gemm_bt(const u16* __restrict__ A,
                                               const u16* __restrict__ Bm,
                                               float* __restrict__ C) {
  __shared__ u16 As[3][256*64];
  __shared__ u16 Bs[3][128*64];
  const int t = threadIdx.x, lane = t & 63, wave = t >> 6;
  int bid = blockIdx.x;
  int nid = ((bid & 7) << 5) | (bid >> 3);
  const int bm = nid >> 3, bn = nid & 7;
  const size_t aBase = (size_t)bm * 256 * KDIM;
  const size_t bBase = (size_t)bn * 128 * KDIM;

  const int srow = t >> 3;
  const int scol = ((t & 7) ^ (srow & 7)) * 8;
  const int dstB = srow * 128 + (t & 7) * 16;

  const int wm = wave >> 2, wn = wave & 3;
  const int la = lane & 15;
  const int lkB = ((lane >> 4) * 16);
  const int rsw = (lane & 7) << 4;

  f32x4 acc[8][2];
#pragma unroll
  for (int m = 0; m < 8; ++m)
#pragma unroll
    for (int n = 0; n < 2; ++n) acc[m][n] = (f32x4){0.f, 0.f, 0.f, 0.f};

  auto stage = [&](int b, int kt) {
    int k0 = kt * 64;
#pragma unroll
    for (int j = 0; j < 4; ++j) {
      __builtin_amdgcn_global_load_lds(
          (const __attribute__((address_space(1))) void*)(A + aBase + (size_t)(j*64 + srow)*KDIM + k0 + scol),
          (__attribute__((address_space(3))) void*)((char*)&As[b][0] + j*8192 + dstB), 16, 0, 0);
    }
#pragma unroll
    for (int j = 0; j < 2; ++j) {
      __builtin_amdgcn_global_load_lds(
          (const __attribute__((address_space(1))) void*)(Bm + bBase + (size_t)(j*64 + srow)*KDIM + k0 + scol),
          (__attribute__((address_space(3))) void*)((char*)&Bs[b][0] + j*8192 + dstB), 16, 0, 0);
    }
  };

  stage(0, 0);
  stage(1, 1);

#pragma clang loop unroll(disable)
  for (int kt = 0; kt < 16; ++kt) {
    const int cur = kt % 3;
    if (kt < 15)
      asm volatile("s_waitcnt vmcnt(6)" ::: "memory");
    else
      asm volatile("s_waitcnt vmcnt(0)" ::: "memory");
    __builtin_amdgcn_s_barrier();
    short8 af[8][2], bf[2][2];
#pragma unroll
    for (int kk = 0; kk < 2; ++kk) {
#pragma unroll
      for (int m = 0; m < 8; ++m) {
        int row = wm*128 + m*16 + la;
        int byt = (row*128 + kk*64 + lkB) ^ rsw;
        af[m][kk] = *(const short8*)((char*)&As[cur][0] + byt);
      }
#pragma unroll
      for (int n = 0; n < 2; ++n) {
        int row = wn*32 + n*16 + la;
        int byt = (row*128 + kk*64 + lkB) ^ rsw;
        bf[n][kk] = *(const short8*)((char*)&Bs[cur][0] + byt);
      }
    }
    if (kt < 14) stage((kt + 2) % 3, kt + 2);
    __builtin_amdgcn_s_setprio(1);
#pragma unroll
    for (int kk = 0; kk < 2; ++kk)
#pragma unroll
      for (int m = 0; m < 8; ++m)
#pragma unroll
        for (int n = 0; n < 2; ++n)
          acc[m][n] = __builtin_amdgcn_mfma_f32_16x16x32_bf16(af[m][kk], bf[n][kk], acc[m][n], 0, 0, 0);
    __builtin_amdgcn_s_setprio(0);
  }

  int orow0 = bm*256 + wm*128 + (lane >> 4)*4;
  int ocol0 = bn*128 + wn*32 + la;
#pragma unroll
  for (int m = 0; m < 8; ++m)
#pragma unroll
    for (int n = 0; n < 2; ++n)
#pragma unroll
      for (int j = 0; j < 4; ++j)
        C[(size_t)(orow0 + m*16 + j)*NDIM + ocol0 + n*16] = acc[m][n][j];
}

extern "C" void kernel_launch(void* const* d_in, const int* in_sizes, int n_in,
                              void* d_out, int out_size, void* d_ws, size_t ws_size,
                              hipStream_t stream) {
  const float* x = (const float*)d_in[0];
  const float* w = (const float*)d_in[1];
  float* out = (float*)d_out;
  char* ws = (char*)d_ws;
  u16* Bmat = (u16*)(ws + 4096);                             // 2 MB
  u16* Abf  = (u16*)(ws + 4096 + 2*1024*1024);               // 16 MB

  fused_front<<<1024, 256, 0, stream>>>(x, w, Abf, Bmat);
  gemm_bt<<<(BATCH/256)*(NDIM/128), 512, 0, stream>>>(Abf, Bmat, out);
}

// Round 21
// 48.071 us; speedup vs baseline: 1.2223x; 1.0315x over previous
//
#include <hip/hip_runtime.h>
#include <stdint.h>

typedef uint16_t u16;
typedef __attribute__((ext_vector_type(2))) float f32x2;
typedef __attribute__((ext_vector_type(4))) float f32x4;
typedef __attribute__((ext_vector_type(8))) short short8;
typedef __attribute__((ext_vector_type(4))) float float4v;
typedef __attribute__((ext_vector_type(4))) uint16_t u16x4;
typedef __attribute__((ext_vector_type(8))) uint16_t u16x8;

#define DIMQ 1024
#define BATCH 8192
#define KDIM 1024
#define NDIM 1024

#define RDL(v, l) __int_as_float(__builtin_amdgcn_readlane(__float_as_int(v), (l)))

__device__ __forceinline__ u16 f2bf(float f) {
  uint32_t u = __float_as_uint(f);
  u += 0x7fffu + ((u >> 16) & 1u);
  return (u16)(u >> 16);
}

// cross-lane xor exchange; DPP (VALU) for 1,2,8; ds_swizzle for 4; shfl for 32.
// (verified R4/R5/R6/R11/R15)
template<int MASK>
__device__ __forceinline__ float lane_xor(float x) {
  if constexpr (MASK == 1)
    return __int_as_float(__builtin_amdgcn_update_dpp(0, __float_as_int(x), 0xB1, 0xF, 0xF, true));
  else if constexpr (MASK == 2)
    return __int_as_float(__builtin_amdgcn_update_dpp(0, __float_as_int(x), 0x4E, 0xF, 0xF, true));
  else if constexpr (MASK == 8)
    return __int_as_float(__builtin_amdgcn_update_dpp(0, __float_as_int(x), 0x128, 0xF, 0xF, true));
  else if constexpr (MASK == 4)
    return __int_as_float(__builtin_amdgcn_ds_swizzle(__float_as_int(x), 0x101F));
  else if constexpr (MASK == 16)
    return __int_as_float(__builtin_amdgcn_ds_swizzle(__float_as_int(x), 0x401F));
  else
    return __shfl_xor(x, 32, 64);
}

// cross-lane gate on 8 regs: batched partner fetch, then PACKED FMAs (verified R14)
template<int MASK>
__device__ __forceinline__ void lane_gate8(float* ar, float* ai, int lane,
    float u00r, float u00i, float u01r, float u01i,
    float u10r, float u10i, float u11r, float u11i) {
  bool hi = (lane & MASK) != 0;
  float cmr = hi ? u11r : u00r, cmi = hi ? u11i : u00i;
  float cor = hi ? u10r : u01r, coi = hi ? u10i : u01i;
  float otr[8], oti[8];
#pragma unroll
  for (int r = 0; r < 8; ++r) otr[r] = lane_xor<MASK>(ar[r]);
#pragma unroll
  for (int r = 0; r < 8; ++r) oti[r] = lane_xor<MASK>(ai[r]);
#pragma unroll
  for (int k = 0; k < 4; ++k) {
    f32x2 A = {ar[2*k], ar[2*k+1]}, I = {ai[2*k], ai[2*k+1]};
    f32x2 R = {otr[2*k], otr[2*k+1]}, J = {oti[2*k], oti[2*k+1]};
    f32x2 nr = A*cmr - I*cmi + R*cor - J*coi;
    f32x2 ni = I*cmr + A*cmi + J*cor + R*coi;
    ar[2*k] = nr[0]; ar[2*k+1] = nr[1];
    ai[2*k] = ni[0]; ai[2*k+1] = ni[1];
  }
}

// packed 2x2 butterfly on two amp pairs at once (verified R14)
__device__ __forceinline__ void bfly2(f32x2 &a0r, f32x2 &a0i, f32x2 &a1r, f32x2 &a1i,
    float u00r, float u00i, float u01r, float u01i,
    float u10r, float u10i, float u11r, float u11i) {
  f32x2 t0r = a0r*u00r - a0i*u00i + a1r*u01r - a1i*u01i;
  f32x2 t0i = a0i*u00r + a0r*u00i + a1i*u01r + a1r*u01i;
  f32x2 t1r = a0r*u10r - a0i*u10i + a1r*u11r - a1i*u11i;
  f32x2 t1i = a0i*u10r + a0r*u10i + a1i*u11r + a1r*u11i;
  a0r = t0r; a0i = t0i; a1r = t1r; a1i = t1i;
}

// complex 2x2 layout: {00r,00i, 01r,01i, 10r,10i, 11r,11i}
__device__ inline void cmul2x2(float* O, const float* A, const float* B) {
  for (int r = 0; r < 2; ++r)
    for (int c = 0; c < 2; ++c) {
      float re = 0.f, im = 0.f;
      for (int j = 0; j < 2; ++j) {
        float ar = A[(r*2+j)*2], ai = A[(r*2+j)*2+1];
        float br = B[(j*2+c)*2], bi = B[(j*2+c)*2+1];
        re += ar*br - ai*bi;
        im += ar*bi + ai*br;
      }
      O[(r*2+c)*2]   = re;
      O[(r*2+c)*2+1] = im;
    }
}
__device__ inline void mk_rx(float* m, float t) {
  float s, c; sincosf(0.5f*t, &s, &c);
  m[0]=c; m[1]=0; m[2]=0; m[3]=-s; m[4]=0; m[5]=-s; m[6]=c; m[7]=0;
}
__device__ inline void mk_ry(float* m, float t) {
  float s, c; sincosf(0.5f*t, &s, &c);
  m[0]=c; m[1]=0; m[2]=-s; m[3]=0; m[4]=s; m[5]=0; m[6]=c; m[7]=0;
}
__device__ inline void mk_rz(float* m, float t) {
  float s, c; sincosf(0.5f*t, &s, &c);
  m[0]=c; m[1]=-s; m[2]=0; m[3]=0; m[4]=0; m[5]=0; m[6]=c; m[7]=s;
}

__device__ __forceinline__ int padi(int y) { return y + (y >> 4); }

// one build stage (R20 structure, 4-SOURCE gather):
// LDS pass applies perm + bit-3 gate (q6) + bit-8 gate (q1) fused as
// K = U6[h] (x) U1[l4] over sources (m3,m8); then reg gates (bits 2..0),
// then remaining lane gates (masks 32,8,4,2,1). One barrier per stage
// (slab double-buffered by parity, verified R20).
// Y[j] = sigma(x_j) ^ h*527 ^ l4*1023  (527=sigma(8), 1023=sigma(256));
// source addr = padi(Y[j] ^ CC[m]), CC = {0,1023,527,496}.
__device__ __forceinline__ void do_stage(int gbase, float (&ar)[8], float (&ai)[8],
    f32x2* __restrict__ slab,
    const int (&Y)[8],
    int wbase, int lane, int h, int l4,
    float O0, float O1, float O2, float O3,
    float O4, float O5, float O6, float O7) {
#pragma unroll
  for (int j = 0; j < 8; ++j) slab[wbase + j] = (f32x2){ar[j], ai[j]};
  __syncthreads();
  {
    const int g6 = gbase + 6, g1 = gbase + 1;
    // U6[h][c], U1[l4][c]
    float u6r0 = h ? RDL(O4,g6) : RDL(O0,g6), u6i0 = h ? RDL(O5,g6) : RDL(O1,g6);
    float u6r1 = h ? RDL(O6,g6) : RDL(O2,g6), u6i1 = h ? RDL(O7,g6) : RDL(O3,g6);
    float u1r0 = l4 ? RDL(O4,g1) : RDL(O0,g1), u1i0 = l4 ? RDL(O5,g1) : RDL(O1,g1);
    float u1r1 = l4 ? RDL(O6,g1) : RDL(O2,g1), u1i1 = l4 ? RDL(O7,g1) : RDL(O3,g1);
    // K[m3*2+m8] = U6[h][m3] * U1[l4][m8]
    float KR[4], KI[4];
    KR[0] = u6r0*u1r0 - u6i0*u1i0;  KI[0] = u6r0*u1i0 + u6i0*u1r0;
    KR[1] = u6r0*u1r1 - u6i0*u1i1;  KI[1] = u6r0*u1i1 + u6i0*u1r1;
    KR[2] = u6r1*u1r0 - u6i1*u1i0;  KI[2] = u6r1*u1i0 + u6i1*u1r0;
    KR[3] = u6r1*u1r1 - u6i1*u1i1;  KI[3] = u6r1*u1i1 + u6i1*u1r1;
    const int CC[4] = {0, 1023, 527, 496};   // {none, s256, s8, s8^s256}
    f32x2 v[8][4];
#pragma unroll
    for (int j = 0; j < 8; ++j)
#pragma unroll
      for (int m = 0; m < 4; ++m)
        v[j][m] = slab[padi(Y[j] ^ CC[m])];
#pragma unroll
    for (int k = 0; k < 4; ++k) {
      f32x2 nr = {0.f, 0.f}, ni = {0.f, 0.f};
#pragma unroll
      for (int m = 0; m < 4; ++m) {
        f32x2 Vr = {v[2*k][m][0], v[2*k+1][m][0]};
        f32x2 Vi = {v[2*k][m][1], v[2*k+1][m][1]};
        nr += Vr*KR[m] - Vi*KI[m];
        ni += Vi*KR[m] + Vr*KI[m];
      }
      ar[2*k] = nr[0]; ar[2*k+1] = nr[1];
      ai[2*k] = ni[0]; ai[2*k+1] = ni[1];
    }
  }
  { int g = gbase + 7;   // p=2: pairs (r, r+4)
    float u0r=RDL(O0,g),u0i=RDL(O1,g),u1r=RDL(O2,g),u1i=RDL(O3,g);
    float u2r=RDL(O4,g),u2i=RDL(O5,g),u3r=RDL(O6,g),u3i=RDL(O7,g);
    f32x2 a0r={ar[0],ar[1]}, a0i={ai[0],ai[1]}, a1r={ar[4],ar[5]}, a1i={ai[4],ai[5]};
    bfly2(a0r,a0i,a1r,a1i, u0r,u0i,u1r,u1i,u2r,u2i,u3r,u3i);
    ar[0]=a0r[0];ar[1]=a0r[1];ai[0]=a0i[0];ai[1]=a0i[1];
    ar[4]=a1r[0];ar[5]=a1r[1];ai[4]=a1i[0];ai[5]=a1i[1];
    f32x2 b0r={ar[2],ar[3]}, b0i={ai[2],ai[3]}, b1r={ar[6],ar[7]}, b1i={ai[6],ai[7]};
    bfly2(b0r,b0i,b1r,b1i, u0r,u0i,u1r,u1i,u2r,u2i,u3r,u3i);
    ar[2]=b0r[0];ar[3]=b0r[1];ai[2]=b0i[0];ai[3]=b0i[1];
    ar[6]=b1r[0];ar[7]=b1r[1];ai[6]=b1i[0];ai[7]=b1i[1];
  }
  { int g = gbase + 8;   // p=1: pairs (r, r+2)
    float u0r=RDL(O0,g),u0i=RDL(O1,g),u1r=RDL(O2,g),u1i=RDL(O3,g);
    float u2r=RDL(O4,g),u2i=RDL(O5,g),u3r=RDL(O6,g),u3i=RDL(O7,g);
    f32x2 a0r={ar[0],ar[1]}, a0i={ai[0],ai[1]}, a1r={ar[2],ar[3]}, a1i={ai[2],ai[3]};
    bfly2(a0r,a0i,a1r,a1i, u0r,u0i,u1r,u1i,u2r,u2i,u3r,u3i);
    ar[0]=a0r[0];ar[1]=a0r[1];ai[0]=a0i[0];ai[1]=a0i[1];
    ar[2]=a1r[0];ar[3]=a1r[1];ai[2]=a1i[0];ai[3]=a1i[1];
    f32x2 b0r={ar[4],ar[5]}, b0i={ai[4],ai[5]}, b1r={ar[6],ar[7]}, b1i={ai[6],ai[7]};
    bfly2(b0r,b0i,b1r,b1i, u0r,u0i,u1r,u1i,u2r,u2i,u3r,u3i);
    ar[4]=b0r[0];ar[5]=b0r[1];ai[4]=b0i[0];ai[5]=b0i[1];
    ar[6]=b1r[0];ar[7]=b1r[1];ai[6]=b1i[0];ai[7]=b1i[1];
  }
  { int g = gbase + 9;   // p=0: pairs (r, r+1), packed along bit 1
    float u0r=RDL(O0,g),u0i=RDL(O1,g),u1r=RDL(O2,g),u1i=RDL(O3,g);
    float u2r=RDL(O4,g),u2i=RDL(O5,g),u3r=RDL(O6,g),u3i=RDL(O7,g);
    f32x2 a0r={ar[0],ar[2]}, a0i={ai[0],ai[2]}, a1r={ar[1],ar[3]}, a1i={ai[1],ai[3]};
    bfly2(a0r,a0i,a1r,a1i, u0r,u0i,u1r,u1i,u2r,u2i,u3r,u3i);
    ar[0]=a0r[0];ar[2]=a0r[1];ai[0]=a0i[0];ai[2]=a0i[1];
    ar[1]=a1r[0];ar[3]=a1r[1];ai[1]=a1i[0];ai[3]=a1i[1];
    f32x2 b0r={ar[4],ar[6]}, b0i={ai[4],ai[6]}, b1r={ar[5],ar[7]}, b1i={ai[5],ai[7]};
    bfly2(b0r,b0i,b1r,b1i, u0r,u0i,u1r,u1i,u2r,u2i,u3r,u3i);
    ar[4]=b0r[0];ar[6]=b0r[1];ai[4]=b0i[0];ai[6]=b0i[1];
    ar[5]=b1r[0];ar[7]=b1r[1];ai[5]=b1i[0];ai[7]=b1i[1];
  }
  // remaining lane gates: masks 32 (q0), 8 (q2), 4 (q3), 2 (q4), 1 (q5)
  { int g = gbase + 0; lane_gate8<32>(ar, ai, lane, RDL(O0,g),RDL(O1,g),RDL(O2,g),RDL(O3,g),RDL(O4,g),RDL(O5,g),RDL(O6,g),RDL(O7,g)); }
  { int g = gbase + 2; lane_gate8< 8>(ar, ai, lane, RDL(O0,g),RDL(O1,g),RDL(O2,g),RDL(O3,g),RDL(O4,g),RDL(O5,g),RDL(O6,g),RDL(O7,g)); }
  { int g = gbase + 3; lane_gate8< 4>(ar, ai, lane, RDL(O0,g),RDL(O1,g),RDL(O2,g),RDL(O3,g),RDL(O4,g),RDL(O5,g),RDL(O6,g),RDL(O7,g)); }
  { int g = gbase + 4; lane_gate8< 2>(ar, ai, lane, RDL(O0,g),RDL(O1,g),RDL(O2,g),RDL(O3,g),RDL(O4,g),RDL(O5,g),RDL(O6,g),RDL(O7,g)); }
  { int g = gbase + 5; lane_gate8< 1>(ar, ai, lane, RDL(O0,g),RDL(O1,g),RDL(O2,g),RDL(O3,g),RDL(O4,g),RDL(O5,g),RDL(O6,g),RDL(O7,g)); }
}

// Fused front (R20 structure; 4-source gather fold).
//   blocks [0, 512):     build — states d0=2*bid (waves 0,1), d1=2*bid+1 (waves 2,3).
//   blocks [512, 1024):  row-normalize x -> bf16, 16 rows per block.
__global__ __launch_bounds__(256) void fused_front(const float* __restrict__ x,
                                                   const float* __restrict__ w,
                                                   u16* __restrict__ Abf,
                                                   u16* __restrict__ Bmat) {
  __shared__ f32x2 slab[2][2][1088];   // [state][stage parity][padded 1024]
  const int bid = blockIdx.x;
  const int lane = threadIdx.x & 63, wv = threadIdx.x >> 6;

  if (bid >= 512) {
    int base = (bid - 512) * 16 + wv * 4;
    for (int it = 0; it < 4; ++it) {
      int row = base + it;
      const float* xr = x + (size_t)row * DIMQ;
      float4v v[4];
      float ss = 0.f;
#pragma unroll
      for (int j = 0; j < 4; ++j) {
        v[j] = *(const float4v*)(xr + j*256 + lane*4);
        ss += v[j][0]*v[j][0] + v[j][1]*v[j][1] + v[j][2]*v[j][2] + v[j][3]*v[j][3];
      }
#pragma unroll
      for (int off = 32; off; off >>= 1) ss += __shfl_xor(ss, off, 64);
      float inv = 1.0f / fmaxf(sqrtf(ss), 1e-12f);
      u16* orow = Abf + (size_t)row * DIMQ;
#pragma unroll
      for (int j = 0; j < 4; ++j) {
        u16x4 o;
#pragma unroll
        for (int e = 0; e < 4; ++e) o[e] = f2bf(v[j][e] * inv);
        *(u16x4*)(orow + j*256 + lane*4) = o;
      }
    }
    return;
  }

  const int s = wv >> 1, h = wv & 1;
  const int l4 = (lane >> 4) & 1;
  const int d = bid * 2 + s;

  float O0, O1, O2, O3, O4, O5, O6, O7;
  {
    float A[8], B[8], C[8], T8[8], O[8];
    int t = lane;
    if (t < 50) {
      if (t < 10) {
        mk_ry(A, -w[120 + t]);
        mk_rz(B, -w[130 + t]);
        mk_ry(C, -w[140 + t]);
      } else {
        int sg = (t - 10) / 10, q = (t - 10) % 10, l = 3 - sg;
        mk_rx(A, -w[l*30 + q]);
        mk_ry(B, -w[l*30 + 10 + q]);
        mk_rz(C, -w[l*30 + 20 + q]);
      }
      cmul2x2(T8, A, B);
      cmul2x2(O, T8, C);
    } else {
#pragma unroll
      for (int j = 0; j < 8; ++j) O[j] = 0.f;
    }
    O0=O[0]; O1=O[1]; O2=O[2]; O3=O[3]; O4=O[4]; O5=O[5]; O6=O[6]; O7=O[7];
  }

  // gather bases: Y[j] = sigma(x_j) ^ h*527 ^ l4*1023  (own-bit folding; sigma
  // GF(2)-linear, verified R6/R11; 527 = sigma(8) matches R17 T-table)
  int Y[8];
#pragma unroll
  for (int j = 0; j < 8; ++j) {
    int xx = (lane << 4) + (h << 3) + j;
    int yy = xx;
#pragma unroll
    for (int qq = 0; qq < 9; ++qq) yy ^= ((yy >> (9 - qq)) & 1) << (8 - qq);
    yy ^= (yy & 1) << 9;
    Y[j] = yy ^ (h ? 527 : 0) ^ (l4 ? 1023 : 0);
  }
  const int wbase = lane * 17 + h * 8;

  float ar[8], ai[8];
  {
    float fr = 1.0f, fi = 0.0f;
#pragma unroll
    for (int p = 4; p <= 9; ++p) {
      const int q = 9 - p;
      int c = (d >> p) & 1;
      float a0r = c ? RDL(O2,q) : RDL(O0,q), a0i = c ? RDL(O3,q) : RDL(O1,q);
      float a1r = c ? RDL(O6,q) : RDL(O4,q), a1i = c ? RDL(O7,q) : RDL(O5,q);
      bool hb = (lane >> (p - 4)) & 1;
      float gr = hb ? a1r : a0r, gi = hb ? a1i : a0i;
      float nr = fr*gr - fi*gi, ni = fr*gi + fi*gr;
      fr = nr; fi = ni;
    }
    {
      int c = (d >> 3) & 1;
      float a0r = c ? RDL(O2,6) : RDL(O0,6), a0i = c ? RDL(O3,6) : RDL(O1,6);
      float a1r = c ? RDL(O6,6) : RDL(O4,6), a1i = c ? RDL(O7,6) : RDL(O5,6);
      float gr = h ? a1r : a0r, gi = h ? a1i : a0i;
      float nr = fr*gr - fi*gi, ni = fr*gi + fi*gr;
      fr = nr; fi = ni;
    }
    float t2r[2], t2i[2], t1r[2], t1i[2], t0r[2], t0i[2];
    {
      int c = (d >> 2) & 1;
      t2r[0] = c ? RDL(O2,7) : RDL(O0,7); t2i[0] = c ? RDL(O3,7) : RDL(O1,7);
      t2r[1] = c ? RDL(O6,7) : RDL(O4,7); t2i[1] = c ? RDL(O7,7) : RDL(O5,7);
    }
    {
      int c = (d >> 1) & 1;
      t1r[0] = c ? RDL(O2,8) : RDL(O0,8); t1i[0] = c ? RDL(O3,8) : RDL(O1,8);
      t1r[1] = c ? RDL(O6,8) : RDL(O4,8); t1i[1] = c ? RDL(O7,8) : RDL(O5,8);
    }
    {
      int c = d & 1;
      t0r[0] = c ? RDL(O2,9) : RDL(O0,9); t0i[0] = c ? RDL(O3,9) : RDL(O1,9);
      t0r[1] = c ? RDL(O6,9) : RDL(O4,9); t0i[1] = c ? RDL(O7,9) : RDL(O5,9);
    }
    float m21r[4], m21i[4];
#pragma unroll
    for (int b2 = 0; b2 < 2; ++b2)
#pragma unroll
      for (int b1 = 0; b1 < 2; ++b1) {
        m21r[b2*2+b1] = t2r[b2]*t1r[b1] - t2i[b2]*t1i[b1];
        m21i[b2*2+b1] = t2r[b2]*t1i[b1] + t2i[b2]*t1r[b1];
      }
#pragma unroll
    for (int j = 0; j < 8; ++j) {
      int hi2 = j >> 1;
      int b0 = j & 1;
      float wr = m21r[hi2]*t0r[b0] - m21i[hi2]*t0i[b0];
      float wi = m21r[hi2]*t0i[b0] + m21i[hi2]*t0r[b0];
      ar[j] = fr*wr - fi*wi;
      ai[j] = fr*wi + fi*wr;
    }
  }

  // stages 1..4, slab parity alternates (one barrier per stage)
  do_stage(10, ar, ai, slab[s][0], Y, wbase, lane, h, l4, O0,O1,O2,O3,O4,O5,O6,O7);
  do_stage(20, ar, ai, slab[s][1], Y, wbase, lane, h, l4, O0,O1,O2,O3,O4,O5,O6,O7);
  do_stage(30, ar, ai, slab[s][0], Y, wbase, lane, h, l4, O0,O1,O2,O3,O4,O5,O6,O7);
  do_stage(40, ar, ai, slab[s][1], Y, wbase, lane, h, l4, O0,O1,O2,O3,O4,O5,O6,O7);

  u16x8 o;
#pragma unroll
  for (int j = 0; j < 8; ++j) o[j] = f2bf(ar[j]);
  *(u16x8*)(Bmat + (size_t)d * DIMQ + lane*16 + h*8) = o;
}

// C[8192,1024] = A * B^T  (bf16 in, fp32 out) — R19/R20 verified.
// BM=256 x BN=128, BK=64, 512 threads, 3 LDS buffers, counted vmcnt(6),
// raw s_barrier, both-sides swizzle, T5 setprio.
__global__ __launch_bounds__(512) void gemm_bt(const u16* __restrict__ A,
                                               const u16* __restrict__ Bm,
                                               float* __restrict__ C) {
  __shared__ u16 As[3][256*64];
  __shared__ u16 Bs[3][128*64];
  const int t = threadIdx.x, lane = t & 63, wave = t >> 6;
  int bid = blockIdx.x;
  int nid = ((bid & 7) << 5) | (bid >> 3);
  const int bm = nid >> 3, bn = nid & 7;
  const size_t aBase = (size_t)bm * 256 * KDIM;
  const size_t bBase = (size_t)bn * 128 * KDIM;

  const int srow = t >> 3;
  const int scol = ((t & 7) ^ (srow & 7)) * 8;
  const int dstB = srow * 128 + (t & 7) * 16;

  const int wm = wave >> 2, wn = wave & 3;
  const int la = lane & 15;
  const int lkB = ((lane >> 4) * 16);
  const int rsw = (lane & 7) << 4;

  f32x4 acc[8][2];
#pragma unroll
  for (int m = 0; m < 8; ++m)
#pragma unroll
    for (int n = 0; n < 2; ++n) acc[m][n] = (f32x4){0.f, 0.f, 0.f, 0.f};

  auto stage = [&](int b, int kt) {
    int k0 = kt * 64;
#pragma unroll
    for (int j = 0; j < 4; ++j) {
      __builtin_amdgcn_global_load_lds(
          (const __attribute__((address_space(1))) void*)(A + aBase + (size_t)(j*64 + srow)*KDIM + k0 + scol),
          (__attribute__((address_space(3))) void*)((char*)&As[b][0] + j*8192 + dstB), 16, 0, 0);
    }
#pragma unroll
    for (int j = 0; j < 2; ++j) {
      __builtin_amdgcn_global_load_lds(
          (const __attribute__((address_space(1))) void*)(Bm + bBase + (size_t)(j*64 + srow)*KDIM + k0 + scol),
          (__attribute__((address_space(3))) void*)((char*)&Bs[b][0] + j*8192 + dstB), 16, 0, 0);
    }
  };

  stage(0, 0);
  stage(1, 1);

#pragma clang loop unroll(disable)
  for (int kt = 0; kt < 16; ++kt) {
    const int cur = kt % 3;
    if (kt < 15)
      asm volatile("s_waitcnt vmcnt(6)" ::: "memory");
    else
      asm volatile("s_waitcnt vmcnt(0)" ::: "memory");
    __builtin_amdgcn_s_barrier();
    short8 af[8][2], bf[2][2];
#pragma unroll
    for (int kk = 0; kk < 2; ++kk) {
#pragma unroll
      for (int m = 0; m < 8; ++m) {
        int row = wm*128 + m*16 + la;
        int byt = (row*128 + kk*64 + lkB) ^ rsw;
        af[m][kk] = *(const short8*)((char*)&As[cur][0] + byt);
      }
#pragma unroll
      for (int n = 0; n < 2; ++n) {
        int row = wn*32 + n*16 + la;
        int byt = (row*128 + kk*64 + lkB) ^ rsw;
        bf[n][kk] = *(const short8*)((char*)&Bs[cur][0] + byt);
      }
    }
    if (kt < 14) stage((kt + 2) % 3, kt + 2);
    __builtin_amdgcn_s_setprio(1);
#pragma unroll
    for (int kk = 0; kk < 2; ++kk)
#pragma unroll
      for (int m = 0; m < 8; ++m)
#pragma unroll
        for (int n = 0; n < 2; ++n)
          acc[m][n] = __builtin_amdgcn_mfma_f32_16x16x32_bf16(af[m][kk], bf[n][kk], acc[m][n], 0, 0, 0);
    __builtin_amdgcn_s_setprio(0);
  }

  int orow0 = bm*256 + wm*128 + (lane >> 4)*4;
  int ocol0 = bn*128 + wn*32 + la;
#pragma unroll
  for (int m = 0; m < 8; ++m)
#pragma unroll
    for (int n = 0; n < 2; ++n)
#pragma unroll
      for (int j = 0; j < 4; ++j)
        C[(size_t)(orow0 + m*16 + j)*NDIM + ocol0 + n*16] = acc[m][n][j];
}

extern "C" void kernel_launch(void* const* d_in, const int* in_sizes, int n_in,
                              void* d_out, int out_size, void* d_ws, size_t ws_size,
                              hipStream_t stream) {
  const float* x = (const float*)d_in[0];
  const float* w = (const float*)d_in[1];
  float* out = (float*)d_out;
  char* ws = (char*)d_ws;
  u16* Bmat = (u16*)(ws + 4096);                             // 2 MB
  u16* Abf  = (u16*)(ws + 4096 + 2*1024*1024);               // 16 MB

  fused_front<<<1024, 256, 0, stream>>>(x, w, Abf, Bmat);
  gemm_bt<<<(BATCH/256)*(NDIM/128), 512, 0, stream>>>(Abf, Bmat, out);
}